// Round 13
// baseline (369.978 us; speedup 1.0000x reference)
//
#include <hip/hip_runtime.h>

#define NN_TOT 208896      // 32*96*68 nodes
#define E_TOT  1671168     // NN_TOT*8 edges
#define B_SZ   32
#define T_SZ   96
#define NPF    68          // nodes per frame
#define HID    128
#define NBINS  204         // 208896 / 1024 nodes per bin
#define CAP    9216        // padded per-bin capacity: mean 8192 + 11 sigma (overflow p ~ 1e-27)
#define NSB    816         // scatter blocks = E_TOT / 2048

typedef _Float16 f16x8 __attribute__((ext_vector_type(8)));
typedef _Float16 f16x2v __attribute__((ext_vector_type(2)));
typedef float f32x4 __attribute__((ext_vector_type(4)));

// ---------------- single-pass scatter into padded bins (+ fused weight prep blocks) ----------------
// LDS-staged: records + final addresses staged in LDS grouped by bin, then flushed with
// consecutive LDS positions -> consecutive global positions within each bin run (coalesced;
// the old path issued 64-way-splintered 4B scattered stores).
__global__ __launch_bounds__(256) void k_scatter(const int* __restrict__ src, const int* __restrict__ dst,
                                                 int* __restrict__ gcur, int* __restrict__ er_tmp,
                                                 const float* __restrict__ Wih, const float* __restrict__ Whh,
                                                 const float* __restrict__ W1, const float* __restrict__ Wm,
                                                 const float* __restrict__ W0, const float* __restrict__ b0,
                                                 _Float16* __restrict__ Wihh, _Float16* __restrict__ Wihl,
                                                 _Float16* __restrict__ W1p, _Float16* __restrict__ Wmp,
                                                 _Float16* __restrict__ Whhp, _Float16* __restrict__ W0h,
                                                 _Float16* __restrict__ b0h) {
    const int bid = blockIdx.x;
    const int tid = threadIdx.x;
    if (bid >= NSB) {
        // ---- weight prep (uniform per-block branch) ----
        int i = (bid - NSB) * 256 + tid;  // 0..49151
        {
            int e = i & 7;
            int lane = (i >> 3) & 63;
            int f = i >> 9;  // 0..95
            int j = f >> 2, kk = f & 3;
            int q = lane >> 4, p = lane & 15;
            float wv = Wih[(size_t)(j * 16 + p) * 128 + kk * 32 + q * 8 + e];
            _Float16 hi = (_Float16)wv;
            Wihh[i] = hi;
            Wihl[i] = (_Float16)(wv - (float)hi);
        }
        {
            int e = i & 7;
            int lane = (i >> 3) & 63;
            int f = i >> 9;  // 0..95
            int kk = f & 3, g = (f >> 2) % 3, wv = f / 12;
            int q = lane >> 4, c = lane & 15;
            Whhp[i] = (_Float16)Whh[(size_t)(g * 128 + 16 * wv + c) * 128 + kk * 32 + q * 8 + e];
        }
        if (i < 16384) {
            int f = i >> 9;          // frag id 0..31
            int j = f >> 2, kk = f & 3;
            int lane = (i >> 3) & 63;
            int e = i & 7;
            int q = lane >> 4, p = lane & 15;
            int k = kk * 32 + q * 8 + e, n = j * 16 + p;
            W1p[i] = (_Float16)W1[k * 128 + n];
            Wmp[i] = (_Float16)Wm[k * 128 + n];
        }
        if (i < 384) W0h[i] = (_Float16)W0[i];
        if (i < 128) b0h[i] = (_Float16)b0[i];
        return;
    }
    __shared__ int hist[NBINS];
    __shared__ int lofs[NBINS];
    __shared__ int lbase[NBINS];
    __shared__ int ts[256];
    __shared__ int recs[2048];
    __shared__ int dsta[2048];
    for (int i = tid; i < NBINS; i += 256) hist[i] = 0;
    __syncthreads();
    const int be = bid * 2048 + tid * 8;
    int s[8], d[8], rk[8];
    *(int4*)&s[0] = *(const int4*)&src[be];
    *(int4*)&s[4] = *(const int4*)&src[be + 4];
    *(int4*)&d[0] = *(const int4*)&dst[be];
    *(int4*)&d[4] = *(const int4*)&dst[be + 4];
#pragma unroll
    for (int j = 0; j < 8; ++j) rk[j] = atomicAdd(&hist[d[j] >> 10], 1);
    __syncthreads();
    // block-local exclusive scan of bin histogram (204 bins, 256 threads)
    {
        int v = (tid < NBINS) ? hist[tid] : 0;
        ts[tid] = v;
        __syncthreads();
        int inc = v;
        for (int off = 1; off < 256; off <<= 1) {
            int add = (tid >= off) ? ts[tid - off] : 0;
            __syncthreads();
            inc += add;
            ts[tid] = inc;
            __syncthreads();
        }
        if (tid < NBINS) lofs[tid] = inc - v;
    }
    // reserve global bin runs
    for (int i = tid; i < NBINS; i += 256) lbase[i] = atomicAdd(&gcur[i], hist[i]);
    __syncthreads();
    // stage records + final global addresses, grouped by bin
#pragma unroll
    for (int j = 0; j < 8; ++j) {
        int b = d[j] >> 10;
        int pos = lofs[b] + rk[j];
        recs[pos] = s[j] | ((d[j] & 1023) << 18);
        dsta[pos] = b * CAP + lbase[b] + rk[j];
    }
    __syncthreads();
    // flush: consecutive LDS positions -> consecutive global addresses within each bin run
#pragma unroll
    for (int it = 0; it < 8; ++it) {
        int p = tid + it * 256;
        er_tmp[dsta[p]] = recs[p];
    }
}

// ---------------- CSR pass C: records register-cached (single global read), LDS count+scan ----
__global__ __launch_bounds__(256) void k_binsort2(const int* __restrict__ er_tmp, const int* __restrict__ gcur,
                                                  const float* __restrict__ x, int* __restrict__ er,
                                                  int2* __restrict__ row2, float4* __restrict__ xd) {
    __shared__ int lcnt[1024];
    __shared__ int lofs[1024];
    __shared__ int ts[256];
    const int tid = threadIdx.x;
    const int nb = blockIdx.x << 10;
    const int base0 = blockIdx.x * CAP;
    for (int i = tid; i < 1024; i += 256) lcnt[i] = 0;
    __syncthreads();
    const int nrec = gcur[blockIdx.x];
    int rec[36];  // 36*256 == CAP
#pragma unroll
    for (int j = 0; j < 36; ++j) {
        int idx = tid + j * 256;
        rec[j] = (idx < nrec) ? er_tmp[base0 + idx] : -1;
    }
#pragma unroll
    for (int j = 0; j < 36; ++j)
        if (rec[j] >= 0) atomicAdd(&lcnt[rec[j] >> 18], 1);
    __syncthreads();
    const int base = tid * 4;
    const int c0 = lcnt[base], c1 = lcnt[base + 1], c2 = lcnt[base + 2], c3 = lcnt[base + 3];
    int ssum = c0 + c1 + c2 + c3;
    ts[tid] = ssum;
    __syncthreads();
    int inc = ssum;
    for (int off = 1; off < 256; off <<= 1) {
        int add = (tid >= off) ? ts[tid - off] : 0;
        __syncthreads();
        inc += add;
        ts[tid] = inc;
        __syncthreads();
    }
    const int b0 = base0 + (inc - ssum);
    lofs[base] = b0;
    lofs[base + 1] = b0 + c0;
    lofs[base + 2] = b0 + c0 + c1;
    lofs[base + 3] = b0 + c0 + c1 + c2;
    row2[nb + base] = make_int2(b0, b0 + c0);
    row2[nb + base + 1] = make_int2(b0 + c0, b0 + c0 + c1);
    row2[nb + base + 2] = make_int2(b0 + c0 + c1, b0 + c0 + c1 + c2);
    row2[nb + base + 3] = make_int2(b0 + c0 + c1 + c2, b0 + ssum);
    {
        const float4* xv = (const float4*)(x + 3 * (size_t)(nb + base));
        float4 a = xv[0], b = xv[1], c = xv[2];
        float i0 = 1.0f / sqrtf(1.f + (float)c0);
        float i1 = 1.0f / sqrtf(1.f + (float)c1);
        float i2 = 1.0f / sqrtf(1.f + (float)c2);
        float i3 = 1.0f / sqrtf(1.f + (float)c3);
        xd[nb + base + 0] = make_float4(a.x * i0, a.y * i0, a.z * i0, i0);
        xd[nb + base + 1] = make_float4(a.w * i1, b.x * i1, b.y * i1, i1);
        xd[nb + base + 2] = make_float4(b.z * i2, b.w * i2, c.x * i2, i2);
        xd[nb + base + 3] = make_float4(c.y * i3, c.z * i3, c.w * i3, i3);
    }
    __syncthreads();
#pragma unroll
    for (int j = 0; j < 36; ++j)
        if (rec[j] >= 0) {
            int p = atomicAdd(&lofs[rec[j] >> 18], 1);
            er[p] = rec[j] & 0x3FFFF;
        }
}

// ---------------- z0: 3-dim GCN0 aggregate, factorized norm ----------------
__global__ __launch_bounds__(256) void k_z0(const float4* __restrict__ xd, const int2* __restrict__ row2,
                                            const int* __restrict__ er, float4* __restrict__ z0out) {
    const int tid = threadIdx.x;
    const int blk = blockIdx.x;
    const int li = tid >> 2;
    const int slot = tid & 3;
    const int n = blk * 64 + li;
    const int2 be2 = row2[n];
    float p0 = 0.f, p1 = 0.f, p2 = 0.f;
    for (int ei = be2.x + slot; ei < be2.y; ei += 4) {
        float4 f = xd[er[ei]];
        p0 += f.x;
        p1 += f.y;
        p2 += f.z;
    }
    p0 += __shfl_xor(p0, 1); p1 += __shfl_xor(p1, 1); p2 += __shfl_xor(p2, 1);
    p0 += __shfl_xor(p0, 2); p1 += __shfl_xor(p1, 2); p2 += __shfl_xor(p2, 2);
    if (slot == 0) {
        const float4 own = xd[n];
        const float w = own.w;
        float4 z;
        z.x = w * (p0 + own.x);
        z.y = w * (p1 + own.y);
        z.z = w * (p2 + own.z);
        z.w = w;
        z0out[n] = z;
    }
}

// ---------------- fused: aggregation + GEMM1 + GEMM2 + frame-pool atomics ----------------
// Block-range sliced (bofs) this round for rocprof visibility (3 launches of 1088 blocks).
__global__ __launch_bounds__(256, 4) void k_agg_mm(const float4* __restrict__ z0, const int2* __restrict__ row2,
                                                   const int* __restrict__ er, const _Float16* __restrict__ W0h,
                                                   const _Float16* __restrict__ b0h, const _Float16* __restrict__ W1p,
                                                   const float* __restrict__ b1, const _Float16* __restrict__ Wmp,
                                                   const float* __restrict__ bm, float* __restrict__ fr32, int bofs) {
    __shared__ __align__(16) _Float16 As[64 * 136];
    __shared__ __align__(16) _Float16 Bs[64 * 136];
    __shared__ float colpart[4 * 2 * 128];  // [wave][frame 0/1][col]
    const int tid = threadIdx.x;
    const int w = tid >> 6, lane = tid & 63;
    const int blk = blockIdx.x + bofs;

    // phase 1: per-lane edge loop, packed f16, all 32 cols in one pass (software-pipelined)
    {
        const int node = blk * 64 + lane;
        const int2 be2 = row2[node];
        const int beg = be2.x, end = be2.y;
        int ei = beg;
        int sa_c = 0, sb_c = 0, sa_n = 0, sb_n = 0;
        float4 za_c, zb_c;
        if (ei + 2 <= end) { sa_c = er[ei]; sb_c = er[ei + 1]; }
        if (ei + 4 <= end) { sa_n = er[ei + 2]; sb_n = er[ei + 3]; }
        const float4 zs = z0[node];
        if (ei + 2 <= end) { za_c = z0[sa_c]; zb_c = z0[sb_c]; }

        const f16x2v* __restrict__ W0p = (const f16x2v*)W0h;
        const f16x2v* __restrict__ b0p = (const f16x2v*)b0h;
        const int pb = w * 16;
        const f16x2v zero2 = {(_Float16)0.f, (_Float16)0.f};
        f16x2v w0p[16], w1p[16], w2p[16], bbp[16];
#pragma unroll
        for (int j = 0; j < 16; ++j) {
            w0p[j] = W0p[pb + j];
            w1p[j] = W0p[64 + pb + j];
            w2p[j] = W0p[128 + pb + j];
            bbp[j] = b0p[pb + j];
        }
        const _Float16 isd = (_Float16)zs.w;
        const f16x2v dnn = {isd, isd};
        f16x2v accp[16];
        {
            _Float16 sx = (_Float16)zs.x, sy = (_Float16)zs.y, sz = (_Float16)zs.z;
            f16x2v zxx = {sx, sx}, zyy = {sy, sy}, zzz = {sz, sz};
#pragma unroll
            for (int j = 0; j < 16; ++j) {
                f16x2v t = zxx * w0p[j] + (zyy * w1p[j] + (zzz * w2p[j] + bbp[j]));
                t = __builtin_elementwise_max(t, zero2);
                accp[j] = t * dnn;
            }
        }
        for (; ei + 2 <= end; ei += 2) {
            float4 za_nv, zb_nv;
            int sa_nn = 0, sb_nn = 0;
            if (ei + 4 <= end) { za_nv = z0[sa_n]; zb_nv = z0[sb_n]; }
            if (ei + 6 <= end) { sa_nn = er[ei + 4]; sb_nn = er[ei + 5]; }
            const float4 za = za_c, zb = zb_c;
            _Float16 ax = (_Float16)za.x, ay = (_Float16)za.y, az = (_Float16)za.z;
            _Float16 aen = (_Float16)za.w;
            _Float16 bx = (_Float16)zb.x, by = (_Float16)zb.y, bz = (_Float16)zb.z;
            _Float16 ben = (_Float16)zb.w;
            f16x2v axx = {ax, ax}, ayy = {ay, ay}, azz = {az, az}, aee = {aen, aen};
            f16x2v bxx = {bx, bx}, byy = {by, by}, bzz = {bz, bz}, bee = {ben, ben};
#pragma unroll
            for (int j = 0; j < 16; ++j) {
                f16x2v t = axx * w0p[j] + (ayy * w1p[j] + (azz * w2p[j] + bbp[j]));
                t = __builtin_elementwise_max(t, zero2);
                accp[j] = t * aee + accp[j];
            }
#pragma unroll
            for (int j = 0; j < 16; ++j) {
                f16x2v t = bxx * w0p[j] + (byy * w1p[j] + (bzz * w2p[j] + bbp[j]));
                t = __builtin_elementwise_max(t, zero2);
                accp[j] = t * bee + accp[j];
            }
            za_c = za_nv; zb_c = zb_nv;
            sa_n = sa_nn; sb_n = sb_nn;
        }
        if (ei < end) {
            float4 za = z0[er[ei]];
            _Float16 ax = (_Float16)za.x, ay = (_Float16)za.y, az = (_Float16)za.z;
            _Float16 aen = (_Float16)za.w;
            f16x2v axx = {ax, ax}, ayy = {ay, ay}, azz = {az, az}, aee = {aen, aen};
#pragma unroll
            for (int j = 0; j < 16; ++j) {
                f16x2v t = axx * w0p[j] + (ayy * w1p[j] + (azz * w2p[j] + bbp[j]));
                t = __builtin_elementwise_max(t, zero2);
                accp[j] = t * aee + accp[j];
            }
        }
        _Float16* dst = &As[lane * 136 + w * 32];
#pragma unroll
        for (int j = 0; j < 16; ++j) *(f16x2v*)(dst + 2 * j) = accp[j] * dnn;
    }
    __syncthreads();

    // phase 2: GEMM1 (As @ W1p + b1, relu) -> Bs (wave-local rows, 136-stride)
    const int q = lane >> 4, c = lane & 15;
    {
        f16x8 afr[4];
#pragma unroll
        for (int kk = 0; kk < 4; ++kk) afr[kk] = *(const f16x8*)(&As[(w * 16 + c) * 136 + kk * 32 + q * 8]);
        const f16x8* __restrict__ Bv = (const f16x8*)W1p;
#pragma unroll
        for (int j = 0; j < 8; ++j) {
            f32x4 cc = {0.f, 0.f, 0.f, 0.f};
#pragma unroll
            for (int kk = 0; kk < 4; ++kk)
                cc = __builtin_amdgcn_mfma_f32_16x16x32_f16(afr[kk], Bv[(j * 4 + kk) * 64 + lane], cc, 0, 0, 0);
            const float bi = b1[j * 16 + c];
#pragma unroll
            for (int r = 0; r < 4; ++r)
                Bs[(w * 16 + q * 4 + r) * 136 + j * 16 + c] = (_Float16)fmaxf(cc[r] + bi, 0.f);
        }
    }
    // Bs rows w*16..w*16+15 are wave-local -> no barrier needed.

    // phase 3: GEMM2 (Bs @ Wmp + bm, relu) + segmented per-frame column sums
    {
        f16x8 afr2[4];
#pragma unroll
        for (int kk = 0; kk < 4; ++kk) afr2[kk] = *(const f16x8*)(&Bs[(w * 16 + c) * 136 + kk * 32 + q * 8]);
        const f16x8* __restrict__ Bv2 = (const f16x8*)Wmp;
        const int f0 = (blk * 64) / NPF;
        const int cut = (f0 + 1) * NPF;          // first node of frame f0+1
        const int rowg0 = blk * 64 + w * 16 + q * 4;
#pragma unroll
        for (int j = 0; j < 8; ++j) {
            f32x4 cc = {0.f, 0.f, 0.f, 0.f};
#pragma unroll
            for (int kk = 0; kk < 4; ++kk)
                cc = __builtin_amdgcn_mfma_f32_16x16x32_f16(afr2[kk], Bv2[(j * 4 + kk) * 64 + lane], cc, 0, 0, 0);
            const float bi = bm[j * 16 + c];
            float sA = 0.f, sB = 0.f;
#pragma unroll
            for (int r = 0; r < 4; ++r) {
                float v = fmaxf(cc[r] + bi, 0.f);
                if (rowg0 + r < cut) sA += v; else sB += v;
            }
            sA += __shfl_xor(sA, 16);
            sA += __shfl_xor(sA, 32);
            sB += __shfl_xor(sB, 16);
            sB += __shfl_xor(sB, 32);
            if (lane < 16) {
                colpart[(w * 2 + 0) * 128 + j * 16 + c] = sA;
                colpart[(w * 2 + 1) * 128 + j * 16 + c] = sB;
            }
        }
    }
    __syncthreads();
    {
        const int f = tid >> 7, col = tid & 127;  // 256 threads = 2 frames x 128 cols
        float s = colpart[(0 * 2 + f) * 128 + col] + colpart[(1 * 2 + f) * 128 + col] +
                  colpart[(2 * 2 + f) * 128 + col] + colpart[(3 * 2 + f) * 128 + col];
        const int f0 = (blk * 64) / NPF;
        if (f == 0) {
            atomicAdd(&fr32[(size_t)f0 * 128 + col], s);
        } else {
            const int f1 = (blk * 64 + 63) / NPF;
            if (f1 != f0) atomicAdd(&fr32[(size_t)f1 * 128 + col], s);
        }
    }
}

// ---------------- gi GEMM: fr32 (mean-scaled, split to hi/lo f16 in-LDS) @ Wih^T -> GIt ----
__global__ __launch_bounds__(256) void k_gi(const float* __restrict__ fr32,
                                            const _Float16* __restrict__ Wihh, const _Float16* __restrict__ Wihl,
                                            const float* __restrict__ bih, const float* __restrict__ bhh,
                                            float* __restrict__ GIt) {
    __shared__ __align__(16) _Float16 Ah[64 * 136];
    __shared__ __align__(16) _Float16 Al[64 * 136];
    const int tid = threadIdx.x;
    const int w = tid >> 6, lane = tid & 63;
    const int q = lane >> 4, p = lane & 15;
    const int nb = blockIdx.x * 64;

    for (int idx = tid; idx < 64 * 128; idx += 256) {
        int row = idx >> 7, col = idx & 127;
        float v = fr32[(size_t)(nb + row) * 128 + col] * (1.0f / NPF);
        _Float16 hi = (_Float16)v;
        Ah[row * 136 + col] = hi;
        Al[row * 136 + col] = (_Float16)(v - (float)hi);
    }
    __syncthreads();

    f16x8 ah[4], al[4];
#pragma unroll
    for (int kk = 0; kk < 4; ++kk) {
        ah[kk] = *(const f16x8*)(&Ah[(w * 16 + p) * 136 + kk * 32 + q * 8]);
        al[kk] = *(const f16x8*)(&Al[(w * 16 + p) * 136 + kk * 32 + q * 8]);
    }
    const f16x8* __restrict__ Bh = (const f16x8*)Wihh;
    const f16x8* __restrict__ Bl = (const f16x8*)Wihl;
    int dr[4];
#pragma unroll
    for (int r = 0; r < 4; ++r) {
        int m = nb + w * 16 + q * 4 + r;
        int bb = m / 96, tt = m - bb * 96;
        dr[r] = (tt * B_SZ + bb) * 384;
    }
#pragma unroll
    for (int j = 0; j < 24; ++j) {
        f32x4 cc = {0.f, 0.f, 0.f, 0.f};
#pragma unroll
        for (int kk = 0; kk < 4; ++kk)
            cc = __builtin_amdgcn_mfma_f32_16x16x32_f16(ah[kk], Bh[(j * 4 + kk) * 64 + lane], cc, 0, 0, 0);
#pragma unroll
        for (int kk = 0; kk < 4; ++kk)
            cc = __builtin_amdgcn_mfma_f32_16x16x32_f16(ah[kk], Bl[(j * 4 + kk) * 64 + lane], cc, 0, 0, 0);
#pragma unroll
        for (int kk = 0; kk < 4; ++kk)
            cc = __builtin_amdgcn_mfma_f32_16x16x32_f16(al[kk], Bh[(j * 4 + kk) * 64 + lane], cc, 0, 0, 0);
        const int o = j * 16 + p;
        const float bias = bih[o] + ((o < 256) ? bhh[o] : 0.f);
        const float scale = (o < 256) ? -1.44269504f : 1.f;
#pragma unroll
        for (int r = 0; r < 4; ++r) GIt[dr[r] + o] = (cc[r] + bias) * scale;
    }
}

// ---------------- GRU recurrence, time-sliced for rocprof visibility (3 launches) ------
#define GRU_SYNC()                                              \
    asm volatile("s_waitcnt lgkmcnt(0)" ::: "memory");          \
    __builtin_amdgcn_s_barrier();                               \
    __builtin_amdgcn_sched_barrier(0);

#define GRU_BODY(PAR, GU, GL, JOFF)                                                                  \
    {                                                                                                \
        const _Float16* rb = hbuf[PAR];                                                              \
        _Float16* wb = hbuf[PAR ^ 1];                                                                \
        f16x8 afr[4];                                                                                \
        _Pragma("unroll") for (int kk = 0; kk < 4; ++kk)                                             \
            afr[kk] = *(const f16x8*)(&rb[c * 144 + kk * 32 + q * 8]);                               \
        const float* lp = pb + (size_t)(JOFF + 2) * STRIDE;                                          \
        _Pragma("unroll") for (int r = 0; r < 4; ++r)                                                \
            _Pragma("unroll") for (int g = 0; g < 3; ++g)                                            \
                GL[r * 3 + g] = lp[r * 384 + g * 128];                                               \
        f32x4 cc[3];                                                                                 \
        _Pragma("unroll") for (int g = 0; g < 3; ++g) {                                              \
            f32x4 a = {0.f, 0.f, 0.f, 0.f};                                                          \
            _Pragma("unroll") for (int kk = 0; kk < 4; ++kk)                                         \
                a = __builtin_amdgcn_mfma_f32_16x16x32_f16(afr[kk], bfr[g][kk], a, 0, 0, 0);         \
            cc[g] = a;                                                                               \
        }                                                                                            \
        _Pragma("unroll") for (int r = 0; r < 4; ++r) {                                              \
            float hn = cc[2][r] + bh2;                                                               \
            float rg = __builtin_amdgcn_rcpf(1.f + exp2f(fmaf(mL2E, cc[0][r], GU[r * 3 + 0])));      \
            float zg = __builtin_amdgcn_rcpf(1.f + exp2f(fmaf(mL2E, cc[1][r], GU[r * 3 + 1])));      \
            float arg = fmaf(rg, hn, GU[r * 3 + 2]);                                                 \
            float u = __builtin_amdgcn_rcpf(exp2f(2.f * L2E * arg) + 1.f);                           \
            float nn = fmaf(-2.f, u, 1.f);                                                           \
            h[r] = fmaf(zg, h[r] - nn, nn);                                                          \
            if (q < 2) wb[(q * 4 + r) * 144 + 16 * w + c] = (_Float16)h[r];                          \
        }                                                                                            \
        GRU_SYNC()                                                                                   \
    }

__global__ __launch_bounds__(512) __attribute__((amdgpu_waves_per_eu(1, 2)))
void k_gru(const float* __restrict__ GIt, const _Float16* __restrict__ Whhp,
           const float* __restrict__ bhh,
           const float* __restrict__ Wc1, const float* __restrict__ bc1,
           const float* __restrict__ Wc2, const float* __restrict__ bc2,
           float* __restrict__ out, float* __restrict__ hst,
           int t0, int iters, int last) {
    __shared__ __align__(16) _Float16 hbuf[2][16 * 144];
    const int tid = threadIdx.x;
    const int w = tid >> 6, lane = tid & 63;
    const int q = lane >> 4, c = lane & 15;
    const int B = blockIdx.x;  // batches 8B..8B+7
    const float L2E = 1.44269504f;
    const float mL2E = -1.44269504f;
    const int STRIDE = B_SZ * 384;

    f16x8 bfr[3][4];
#pragma unroll
    for (int g = 0; g < 3; ++g)
#pragma unroll
        for (int kk = 0; kk < 4; ++kk)
            bfr[g][kk] = *(const f16x8*)(Whhp + (size_t)(((w * 3 + g) * 4 + kk) * 64 + lane) * 8);
    const float bh2 = bhh[256 + 16 * w + c];
    for (int i = tid; i < 2 * 16 * 144 / 2; i += 512) ((unsigned int*)hbuf)[i] = 0u;
    float h[4] = {0.f, 0.f, 0.f, 0.f};

    const int qq = (q < 2) ? q : 1;  // lanes for rows 8-15 duplicate rows 4-7's addresses
    if (t0 != 0) {
#pragma unroll
        for (int r = 0; r < 4; ++r) h[r] = hst[(size_t)(B * 8 + qq * 4 + r) * 128 + 16 * w + c];
    }
    const float* pb = GIt + (size_t)t0 * STRIDE + (size_t)(B * 8 + qq * 4) * 384 + 16 * w + c;
    float g0[12], g1[12], g2[12];
#pragma unroll
    for (int r = 0; r < 4; ++r)
#pragma unroll
        for (int g = 0; g < 3; ++g) {
            g0[r * 3 + g] = pb[r * 384 + g * 128];
            g1[r * 3 + g] = pb[STRIDE + r * 384 + g * 128];
        }
    __syncthreads();  // hbuf zero-init visible
    if (t0 != 0 && q < 2) {
#pragma unroll
        for (int r = 0; r < 4; ++r) hbuf[0][(q * 4 + r) * 144 + 16 * w + c] = (_Float16)h[r];
    }
    GRU_SYNC()

    for (int it = 0; it < iters; ++it) {
        GRU_BODY(0, g0, g2, 0)
        GRU_BODY(1, g1, g0, 1)
        GRU_BODY(0, g2, g1, 2)
        GRU_BODY(1, g0, g2, 3)
        GRU_BODY(0, g1, g0, 4)
        GRU_BODY(1, g2, g1, 5)
        pb += 6 * (size_t)STRIDE;
    }

    if (!last) {
        if (q < 2) {
#pragma unroll
            for (int r = 0; r < 4; ++r) hst[(size_t)(B * 8 + q * 4 + r) * 128 + 16 * w + c] = h[r];
        }
        return;
    }

    // ---- block-local classifier: this block owns batches 8B..8B+7 entirely ----
    float* hbf = (float*)hbuf;        // 8 x 128 f32 = 4KB (hbuf no longer needed)
    float* hid = hbf + 1024;          // 8 x 64 f32 = 2KB
    __syncthreads();
    if (q < 2) {
#pragma unroll
        for (int r = 0; r < 4; ++r) hbf[(q * 4 + r) * 128 + 16 * w + c] = h[r];
    }
    __syncthreads();
    {
        const int b = tid >> 6, j = tid & 63;  // 512 threads = 8 batches x 64 cols
        const float* hb = hbf + b * 128;
        float a0 = bc1[j], a1 = 0.f, a2 = 0.f, a3 = 0.f;
#pragma unroll
        for (int k = 0; k < 128; k += 4) {
            a0 = fmaf(hb[k], Wc1[k * 64 + j], a0);
            a1 = fmaf(hb[k + 1], Wc1[(k + 1) * 64 + j], a1);
            a2 = fmaf(hb[k + 2], Wc1[(k + 2) * 64 + j], a2);
            a3 = fmaf(hb[k + 3], Wc1[(k + 3) * 64 + j], a3);
        }
        hid[tid] = fmaxf((a0 + a1) + (a2 + a3), 0.f);
    }
    __syncthreads();
    if (tid < 80) {
        int b = tid / 10, cc2 = tid % 10;
        float a = bc2[cc2];
#pragma unroll 8
        for (int k = 0; k < 64; ++k) a = fmaf(hid[b * 64 + k], Wc2[k * 10 + cc2], a);
        out[(B * 8 + b) * 10 + cc2] = a;
    }
}

extern "C" void kernel_launch(void* const* d_in, const int* in_sizes, int n_in, void* d_out, int out_size, void* d_ws,
                              size_t ws_size, hipStream_t stream) {
    const float* x = (const float*)d_in[0];
    const int* ei = (const int*)d_in[1];
    const int* e_src = ei;
    const int* e_dst = ei + E_TOT;
    const float* W0 = (const float*)d_in[2];
    const float* b0 = (const float*)d_in[3];
    const float* W1 = (const float*)d_in[4];
    const float* b1 = (const float*)d_in[5];
    const float* Wm = (const float*)d_in[6];
    const float* bm = (const float*)d_in[7];
    const float* Wih = (const float*)d_in[8];
    const float* Whh = (const float*)d_in[9];
    const float* bih = (const float*)d_in[10];
    const float* bhh = (const float*)d_in[11];
    const float* Wc1 = (const float*)d_in[12];
    const float* bc1 = (const float*)d_in[13];
    const float* Wc2 = (const float*)d_in[14];
    const float* bc2 = (const float*)d_in[15];
    float* out = (float*)d_out;

    char* base = (char*)d_ws;
    size_t off = 0;
    auto alloc = [&](size_t bytes) {
        size_t o = off;
        off = (off + bytes + 255) & ~(size_t)255;
        return o;
    };
    size_t o_gcur = alloc(256 * 4);
    size_t o_row2 = alloc((size_t)NN_TOT * 8);
    size_t o_er = alloc((size_t)NBINS * CAP * 4);      // padded per-bin src-only records
    size_t o_ertmp = alloc((size_t)NBINS * CAP * 4);   // padded per-bin packed (src|ldst<<18)
    size_t o_xd = alloc((size_t)NN_TOT * 16);
    size_t o_fr32 = alloc((size_t)B_SZ * T_SZ * 128 * 4);      // frame pool accumulator (f32)
    size_t o_gi = alloc((size_t)(T_SZ + 2) * B_SZ * 384 * 4);  // +2 steps: branchless tail prefetch
    size_t o_hst = alloc((size_t)B_SZ * 128 * 4);              // GRU h checkpoint (time-slice handoff)
    size_t o_wihh = alloc((size_t)384 * 128 * 2);
    size_t o_wihl = alloc((size_t)384 * 128 * 2);
    size_t o_w1p = alloc((size_t)128 * 128 * 2);
    size_t o_wmp = alloc((size_t)128 * 128 * 2);
    size_t o_whhp = alloc((size_t)128 * 384 * 2);
    size_t o_w0h = alloc((size_t)384 * 2);
    size_t o_b0h = alloc((size_t)128 * 2);
    size_t o_z0 = alloc((size_t)NN_TOT * 16);
    if (off > ws_size) return;

    int* gcur = (int*)(base + o_gcur);
    int2* row2 = (int2*)(base + o_row2);
    int* er = (int*)(base + o_er);
    int* er_tmp = (int*)(base + o_ertmp);
    float4* xd = (float4*)(base + o_xd);
    float* fr32 = (float*)(base + o_fr32);
    float* GIt = (float*)(base + o_gi);
    float* hst = (float*)(base + o_hst);
    _Float16* Wihh = (_Float16*)(base + o_wihh);
    _Float16* Wihl = (_Float16*)(base + o_wihl);
    _Float16* W1p = (_Float16*)(base + o_w1p);
    _Float16* Wmp = (_Float16*)(base + o_wmp);
    _Float16* Whhp = (_Float16*)(base + o_whhp);
    _Float16* W0h = (_Float16*)(base + o_w0h);
    _Float16* b0h = (_Float16*)(base + o_b0h);
    float4* z0 = (float4*)(base + o_z0);

    hipMemsetAsync(base + o_gcur, 0, 256 * 4, stream);                         // bin cursors
    hipMemsetAsync(base + o_fr32, 0, (size_t)B_SZ * T_SZ * 128 * 4, stream);   // pool accumulator

    k_scatter<<<NSB + 192, 256, 0, stream>>>(e_src, e_dst, gcur, er_tmp,
                                             Wih, Whh, W1, Wm, W0, b0,
                                             Wihh, Wihl, W1p, Wmp, Whhp, W0h, b0h);
    k_binsort2<<<NBINS, 256, 0, stream>>>(er_tmp, gcur, x, er, row2, xd);
    k_z0<<<NN_TOT / 64, 256, 0, stream>>>(xd, row2, er, z0);
    // agg_mm block-range sliced this round (visibility: pieces ~26us surface the next-biggest kernel)
    k_agg_mm<<<1088, 256, 0, stream>>>(z0, row2, er, W0h, b0h, W1p, b1, Wmp, bm, fr32, 0);
    k_agg_mm<<<1088, 256, 0, stream>>>(z0, row2, er, W0h, b0h, W1p, b1, Wmp, bm, fr32, 1088);
    k_agg_mm<<<1088, 256, 0, stream>>>(z0, row2, er, W0h, b0h, W1p, b1, Wmp, bm, fr32, 2176);
    k_gi<<<B_SZ * T_SZ / 64, 256, 0, stream>>>(fr32, Wihh, Wihl, bih, bhh, GIt);
    // time-sliced GRU
    k_gru<<<4, 512, 0, stream>>>(GIt, Whhp, bhh, Wc1, bc1, Wc2, bc2, out, hst, 0, 5, 0);
    k_gru<<<4, 512, 0, stream>>>(GIt, Whhp, bhh, Wc1, bc1, Wc2, bc2, out, hst, 30, 5, 0);
    k_gru<<<4, 512, 0, stream>>>(GIt, Whhp, bhh, Wc1, bc1, Wc2, bc2, out, hst, 60, 6, 1);
}

// Round 14
// 338.313 us; speedup vs baseline: 1.0936x; 1.0936x over previous
//
#include <hip/hip_runtime.h>

#define NN_TOT 208896      // 32*96*68 nodes
#define E_TOT  1671168     // NN_TOT*8 edges
#define B_SZ   32
#define T_SZ   96
#define NPF    68          // nodes per frame
#define HID    128
#define NBINS  204         // 208896 / 1024 nodes per bin
#define CAP    9216        // padded per-bin capacity: mean 8192 + 11 sigma (overflow p ~ 1e-27)
#define NSB    816         // scatter blocks = E_TOT / 2048

typedef _Float16 f16x8 __attribute__((ext_vector_type(8)));
typedef _Float16 f16x2v __attribute__((ext_vector_type(2)));
typedef float f32x4 __attribute__((ext_vector_type(4)));

// ---------------- single-pass scatter into padded bins (+ fused weight prep + fr32 zero) ----------
// LDS-staged coalesced flush. Prep blocks [816,1008) also zero the fr32 pool accumulator
// (192*256*8 = 393216 floats exactly) — saves a separate memset dispatch; fr32 is first
// consumed by k_agg_mm, 3 launches later, so ordering is safe.
__global__ __launch_bounds__(256) void k_scatter(const int* __restrict__ src, const int* __restrict__ dst,
                                                 int* __restrict__ gcur, int* __restrict__ er_tmp,
                                                 const float* __restrict__ Wih, const float* __restrict__ Whh,
                                                 const float* __restrict__ W1, const float* __restrict__ Wm,
                                                 const float* __restrict__ W0, const float* __restrict__ b0,
                                                 _Float16* __restrict__ Wihh, _Float16* __restrict__ Wihl,
                                                 _Float16* __restrict__ W1p, _Float16* __restrict__ Wmp,
                                                 _Float16* __restrict__ Whhp, _Float16* __restrict__ W0h,
                                                 _Float16* __restrict__ b0h, float4* __restrict__ fr32v) {
    const int bid = blockIdx.x;
    const int tid = threadIdx.x;
    if (bid >= NSB) {
        // ---- weight prep (uniform per-block branch) ----
        int i = (bid - NSB) * 256 + tid;  // 0..49151
        {
            // fr32 zero-fill: 2 float4 per thread -> 49152*8 = 393216 floats exactly
            const float4 z4 = make_float4(0.f, 0.f, 0.f, 0.f);
            fr32v[(size_t)i * 2] = z4;
            fr32v[(size_t)i * 2 + 1] = z4;
        }
        {
            int e = i & 7;
            int lane = (i >> 3) & 63;
            int f = i >> 9;  // 0..95
            int j = f >> 2, kk = f & 3;
            int q = lane >> 4, p = lane & 15;
            float wv = Wih[(size_t)(j * 16 + p) * 128 + kk * 32 + q * 8 + e];
            _Float16 hi = (_Float16)wv;
            Wihh[i] = hi;
            Wihl[i] = (_Float16)(wv - (float)hi);
        }
        {
            int e = i & 7;
            int lane = (i >> 3) & 63;
            int f = i >> 9;  // 0..95
            int kk = f & 3, g = (f >> 2) % 3, wv = f / 12;
            int q = lane >> 4, c = lane & 15;
            Whhp[i] = (_Float16)Whh[(size_t)(g * 128 + 16 * wv + c) * 128 + kk * 32 + q * 8 + e];
        }
        if (i < 16384) {
            int f = i >> 9;          // frag id 0..31
            int j = f >> 2, kk = f & 3;
            int lane = (i >> 3) & 63;
            int e = i & 7;
            int q = lane >> 4, p = lane & 15;
            int k = kk * 32 + q * 8 + e, n = j * 16 + p;
            W1p[i] = (_Float16)W1[k * 128 + n];
            Wmp[i] = (_Float16)Wm[k * 128 + n];
        }
        if (i < 384) W0h[i] = (_Float16)W0[i];
        if (i < 128) b0h[i] = (_Float16)b0[i];
        return;
    }
    __shared__ int hist[NBINS];
    __shared__ int lofs[NBINS];
    __shared__ int lbase[NBINS];
    __shared__ int ts[256];
    __shared__ int recs[2048];
    __shared__ int dsta[2048];
    for (int i = tid; i < NBINS; i += 256) hist[i] = 0;
    __syncthreads();
    const int be = bid * 2048 + tid * 8;
    int s[8], d[8], rk[8];
    *(int4*)&s[0] = *(const int4*)&src[be];
    *(int4*)&s[4] = *(const int4*)&src[be + 4];
    *(int4*)&d[0] = *(const int4*)&dst[be];
    *(int4*)&d[4] = *(const int4*)&dst[be + 4];
#pragma unroll
    for (int j = 0; j < 8; ++j) rk[j] = atomicAdd(&hist[d[j] >> 10], 1);
    __syncthreads();
    // block-local exclusive scan of bin histogram (204 bins, 256 threads)
    {
        int v = (tid < NBINS) ? hist[tid] : 0;
        ts[tid] = v;
        __syncthreads();
        int inc = v;
        for (int off = 1; off < 256; off <<= 1) {
            int add = (tid >= off) ? ts[tid - off] : 0;
            __syncthreads();
            inc += add;
            ts[tid] = inc;
            __syncthreads();
        }
        if (tid < NBINS) lofs[tid] = inc - v;
    }
    // reserve global bin runs
    for (int i = tid; i < NBINS; i += 256) lbase[i] = atomicAdd(&gcur[i], hist[i]);
    __syncthreads();
    // stage records + final global addresses, grouped by bin
#pragma unroll
    for (int j = 0; j < 8; ++j) {
        int b = d[j] >> 10;
        int pos = lofs[b] + rk[j];
        recs[pos] = s[j] | ((d[j] & 1023) << 18);
        dsta[pos] = b * CAP + lbase[b] + rk[j];
    }
    __syncthreads();
    // flush: consecutive LDS positions -> consecutive global addresses within each bin run
#pragma unroll
    for (int it = 0; it < 8; ++it) {
        int p = tid + it * 256;
        er_tmp[dsta[p]] = recs[p];
    }
}

// ---------------- CSR pass C: rank captured in the counting pass (no second atomic pass) ----
__global__ __launch_bounds__(256) void k_binsort2(const int* __restrict__ er_tmp, const int* __restrict__ gcur,
                                                  const float* __restrict__ x, int* __restrict__ er,
                                                  int2* __restrict__ row2, float4* __restrict__ xd) {
    __shared__ int lcnt[1024];
    __shared__ int lofs[1024];   // row-start offsets (read-only after scan)
    __shared__ int ts[256];
    const int tid = threadIdx.x;
    const int nb = blockIdx.x << 10;
    const int base0 = blockIdx.x * CAP;
    for (int i = tid; i < 1024; i += 256) lcnt[i] = 0;
    __syncthreads();
    const int nrec = gcur[blockIdx.x];
    // load all bin records once into registers (static unroll -> VGPRs, rule #20)
    int rec[36];  // 36*256 == CAP
    int rnk[36];  // within-node rank from the counting atomicAdd
#pragma unroll
    for (int j = 0; j < 36; ++j) {
        int idx = tid + j * 256;
        rec[j] = (idx < nrec) ? er_tmp[base0 + idx] : -1;
    }
#pragma unroll
    for (int j = 0; j < 36; ++j)
        rnk[j] = (rec[j] >= 0) ? atomicAdd(&lcnt[rec[j] >> 18], 1) : 0;
    __syncthreads();
    const int base = tid * 4;
    const int c0 = lcnt[base], c1 = lcnt[base + 1], c2 = lcnt[base + 2], c3 = lcnt[base + 3];
    int ssum = c0 + c1 + c2 + c3;
    ts[tid] = ssum;
    __syncthreads();
    int inc = ssum;
    for (int off = 1; off < 256; off <<= 1) {
        int add = (tid >= off) ? ts[tid - off] : 0;
        __syncthreads();
        inc += add;
        ts[tid] = inc;
        __syncthreads();
    }
    const int b0 = base0 + (inc - ssum);
    lofs[base] = b0;
    lofs[base + 1] = b0 + c0;
    lofs[base + 2] = b0 + c0 + c1;
    lofs[base + 3] = b0 + c0 + c1 + c2;
    row2[nb + base] = make_int2(b0, b0 + c0);
    row2[nb + base + 1] = make_int2(b0 + c0, b0 + c0 + c1);
    row2[nb + base + 2] = make_int2(b0 + c0 + c1, b0 + c0 + c1 + c2);
    row2[nb + base + 3] = make_int2(b0 + c0 + c1 + c2, b0 + ssum);
    {
        const float4* xv = (const float4*)(x + 3 * (size_t)(nb + base));
        float4 a = xv[0], b = xv[1], c = xv[2];
        float i0 = 1.0f / sqrtf(1.f + (float)c0);
        float i1 = 1.0f / sqrtf(1.f + (float)c1);
        float i2 = 1.0f / sqrtf(1.f + (float)c2);
        float i3 = 1.0f / sqrtf(1.f + (float)c3);
        xd[nb + base + 0] = make_float4(a.x * i0, a.y * i0, a.z * i0, i0);
        xd[nb + base + 1] = make_float4(a.w * i1, b.x * i1, b.y * i1, i1);
        xd[nb + base + 2] = make_float4(b.z * i2, b.w * i2, c.x * i2, i2);
        xd[nb + base + 3] = make_float4(c.y * i3, c.z * i3, c.w * i3, i3);
    }
    __syncthreads();
#pragma unroll
    for (int j = 0; j < 36; ++j)
        if (rec[j] >= 0) er[lofs[rec[j] >> 18] + rnk[j]] = rec[j] & 0x3FFFF;
}

// ---------------- z0: 3-dim GCN0 aggregate, factorized norm ----------------
__global__ __launch_bounds__(256) void k_z0(const float4* __restrict__ xd, const int2* __restrict__ row2,
                                            const int* __restrict__ er, float4* __restrict__ z0out) {
    const int tid = threadIdx.x;
    const int blk = blockIdx.x;
    const int li = tid >> 2;
    const int slot = tid & 3;
    const int n = blk * 64 + li;
    const int2 be2 = row2[n];
    float p0 = 0.f, p1 = 0.f, p2 = 0.f;
    for (int ei = be2.x + slot; ei < be2.y; ei += 4) {
        float4 f = xd[er[ei]];
        p0 += f.x;
        p1 += f.y;
        p2 += f.z;
    }
    p0 += __shfl_xor(p0, 1); p1 += __shfl_xor(p1, 1); p2 += __shfl_xor(p2, 1);
    p0 += __shfl_xor(p0, 2); p1 += __shfl_xor(p1, 2); p2 += __shfl_xor(p2, 2);
    if (slot == 0) {
        const float4 own = xd[n];
        const float w = own.w;
        float4 z;
        z.x = w * (p0 + own.x);
        z.y = w * (p1 + own.y);
        z.z = w * (p2 + own.z);
        z.w = w;
        z0out[n] = z;
    }
}

// ---------------- fused: aggregation + GEMM1 + GEMM2 + frame-pool atomics ----------------
__global__ __launch_bounds__(256, 4) void k_agg_mm(const float4* __restrict__ z0, const int2* __restrict__ row2,
                                                   const int* __restrict__ er, const _Float16* __restrict__ W0h,
                                                   const _Float16* __restrict__ b0h, const _Float16* __restrict__ W1p,
                                                   const float* __restrict__ b1, const _Float16* __restrict__ Wmp,
                                                   const float* __restrict__ bm, float* __restrict__ fr32) {
    __shared__ __align__(16) _Float16 As[64 * 136];
    __shared__ __align__(16) _Float16 Bs[64 * 136];
    __shared__ float colpart[4 * 2 * 128];  // [wave][frame 0/1][col]
    const int tid = threadIdx.x;
    const int w = tid >> 6, lane = tid & 63;
    const int blk = blockIdx.x;

    // phase 1: per-lane edge loop, packed f16, all 32 cols in one pass (software-pipelined)
    {
        const int node = blk * 64 + lane;
        const int2 be2 = row2[node];
        const int beg = be2.x, end = be2.y;
        int ei = beg;
        int sa_c = 0, sb_c = 0, sa_n = 0, sb_n = 0;
        float4 za_c, zb_c;
        if (ei + 2 <= end) { sa_c = er[ei]; sb_c = er[ei + 1]; }
        if (ei + 4 <= end) { sa_n = er[ei + 2]; sb_n = er[ei + 3]; }
        const float4 zs = z0[node];
        if (ei + 2 <= end) { za_c = z0[sa_c]; zb_c = z0[sb_c]; }

        const f16x2v* __restrict__ W0p = (const f16x2v*)W0h;
        const f16x2v* __restrict__ b0p = (const f16x2v*)b0h;
        const int pb = w * 16;
        const f16x2v zero2 = {(_Float16)0.f, (_Float16)0.f};
        f16x2v w0p[16], w1p[16], w2p[16], bbp[16];
#pragma unroll
        for (int j = 0; j < 16; ++j) {
            w0p[j] = W0p[pb + j];
            w1p[j] = W0p[64 + pb + j];
            w2p[j] = W0p[128 + pb + j];
            bbp[j] = b0p[pb + j];
        }
        const _Float16 isd = (_Float16)zs.w;
        const f16x2v dnn = {isd, isd};
        f16x2v accp[16];
        {
            _Float16 sx = (_Float16)zs.x, sy = (_Float16)zs.y, sz = (_Float16)zs.z;
            f16x2v zxx = {sx, sx}, zyy = {sy, sy}, zzz = {sz, sz};
#pragma unroll
            for (int j = 0; j < 16; ++j) {
                f16x2v t = zxx * w0p[j] + (zyy * w1p[j] + (zzz * w2p[j] + bbp[j]));
                t = __builtin_elementwise_max(t, zero2);
                accp[j] = t * dnn;
            }
        }
        for (; ei + 2 <= end; ei += 2) {
            float4 za_nv, zb_nv;
            int sa_nn = 0, sb_nn = 0;
            if (ei + 4 <= end) { za_nv = z0[sa_n]; zb_nv = z0[sb_n]; }
            if (ei + 6 <= end) { sa_nn = er[ei + 4]; sb_nn = er[ei + 5]; }
            const float4 za = za_c, zb = zb_c;
            _Float16 ax = (_Float16)za.x, ay = (_Float16)za.y, az = (_Float16)za.z;
            _Float16 aen = (_Float16)za.w;
            _Float16 bx = (_Float16)zb.x, by = (_Float16)zb.y, bz = (_Float16)zb.z;
            _Float16 ben = (_Float16)zb.w;
            f16x2v axx = {ax, ax}, ayy = {ay, ay}, azz = {az, az}, aee = {aen, aen};
            f16x2v bxx = {bx, bx}, byy = {by, by}, bzz = {bz, bz}, bee = {ben, ben};
#pragma unroll
            for (int j = 0; j < 16; ++j) {
                f16x2v t = axx * w0p[j] + (ayy * w1p[j] + (azz * w2p[j] + bbp[j]));
                t = __builtin_elementwise_max(t, zero2);
                accp[j] = t * aee + accp[j];
            }
#pragma unroll
            for (int j = 0; j < 16; ++j) {
                f16x2v t = bxx * w0p[j] + (byy * w1p[j] + (bzz * w2p[j] + bbp[j]));
                t = __builtin_elementwise_max(t, zero2);
                accp[j] = t * bee + accp[j];
            }
            za_c = za_nv; zb_c = zb_nv;
            sa_n = sa_nn; sb_n = sb_nn;
        }
        if (ei < end) {
            float4 za = z0[er[ei]];
            _Float16 ax = (_Float16)za.x, ay = (_Float16)za.y, az = (_Float16)za.z;
            _Float16 aen = (_Float16)za.w;
            f16x2v axx = {ax, ax}, ayy = {ay, ay}, azz = {az, az}, aee = {aen, aen};
#pragma unroll
            for (int j = 0; j < 16; ++j) {
                f16x2v t = axx * w0p[j] + (ayy * w1p[j] + (azz * w2p[j] + bbp[j]));
                t = __builtin_elementwise_max(t, zero2);
                accp[j] = t * aee + accp[j];
            }
        }
        _Float16* dst = &As[lane * 136 + w * 32];
#pragma unroll
        for (int j = 0; j < 16; ++j) *(f16x2v*)(dst + 2 * j) = accp[j] * dnn;
    }
    __syncthreads();

    // phase 2: GEMM1 (As @ W1p + b1, relu) -> Bs (wave-local rows, 136-stride)
    const int q = lane >> 4, c = lane & 15;
    {
        f16x8 afr[4];
#pragma unroll
        for (int kk = 0; kk < 4; ++kk) afr[kk] = *(const f16x8*)(&As[(w * 16 + c) * 136 + kk * 32 + q * 8]);
        const f16x8* __restrict__ Bv = (const f16x8*)W1p;
#pragma unroll
        for (int j = 0; j < 8; ++j) {
            f32x4 cc = {0.f, 0.f, 0.f, 0.f};
#pragma unroll
            for (int kk = 0; kk < 4; ++kk)
                cc = __builtin_amdgcn_mfma_f32_16x16x32_f16(afr[kk], Bv[(j * 4 + kk) * 64 + lane], cc, 0, 0, 0);
            const float bi = b1[j * 16 + c];
#pragma unroll
            for (int r = 0; r < 4; ++r)
                Bs[(w * 16 + q * 4 + r) * 136 + j * 16 + c] = (_Float16)fmaxf(cc[r] + bi, 0.f);
        }
    }
    // Bs rows w*16..w*16+15 are wave-local -> no barrier needed.

    // phase 3: GEMM2 (Bs @ Wmp + bm, relu) + segmented per-frame column sums
    {
        f16x8 afr2[4];
#pragma unroll
        for (int kk = 0; kk < 4; ++kk) afr2[kk] = *(const f16x8*)(&Bs[(w * 16 + c) * 136 + kk * 32 + q * 8]);
        const f16x8* __restrict__ Bv2 = (const f16x8*)Wmp;
        const int f0 = (blk * 64) / NPF;
        const int cut = (f0 + 1) * NPF;          // first node of frame f0+1
        const int rowg0 = blk * 64 + w * 16 + q * 4;
#pragma unroll
        for (int j = 0; j < 8; ++j) {
            f32x4 cc = {0.f, 0.f, 0.f, 0.f};
#pragma unroll
            for (int kk = 0; kk < 4; ++kk)
                cc = __builtin_amdgcn_mfma_f32_16x16x32_f16(afr2[kk], Bv2[(j * 4 + kk) * 64 + lane], cc, 0, 0, 0);
            const float bi = bm[j * 16 + c];
            float sA = 0.f, sB = 0.f;
#pragma unroll
            for (int r = 0; r < 4; ++r) {
                float v = fmaxf(cc[r] + bi, 0.f);
                if (rowg0 + r < cut) sA += v; else sB += v;
            }
            sA += __shfl_xor(sA, 16);
            sA += __shfl_xor(sA, 32);
            sB += __shfl_xor(sB, 16);
            sB += __shfl_xor(sB, 32);
            if (lane < 16) {
                colpart[(w * 2 + 0) * 128 + j * 16 + c] = sA;
                colpart[(w * 2 + 1) * 128 + j * 16 + c] = sB;
            }
        }
    }
    __syncthreads();
    {
        const int f = tid >> 7, col = tid & 127;  // 256 threads = 2 frames x 128 cols
        float s = colpart[(0 * 2 + f) * 128 + col] + colpart[(1 * 2 + f) * 128 + col] +
                  colpart[(2 * 2 + f) * 128 + col] + colpart[(3 * 2 + f) * 128 + col];
        const int f0 = (blk * 64) / NPF;
        if (f == 0) {
            atomicAdd(&fr32[(size_t)f0 * 128 + col], s);
        } else {
            const int f1 = (blk * 64 + 63) / NPF;
            if (f1 != f0) atomicAdd(&fr32[(size_t)f1 * 128 + col], s);
        }
    }
}

// ---------------- gi GEMM: fr32 (mean-scaled, split to hi/lo f16 in-LDS) @ Wih^T -> GIt ----
__global__ __launch_bounds__(256) void k_gi(const float* __restrict__ fr32,
                                            const _Float16* __restrict__ Wihh, const _Float16* __restrict__ Wihl,
                                            const float* __restrict__ bih, const float* __restrict__ bhh,
                                            float* __restrict__ GIt) {
    __shared__ __align__(16) _Float16 Ah[64 * 136];
    __shared__ __align__(16) _Float16 Al[64 * 136];
    const int tid = threadIdx.x;
    const int w = tid >> 6, lane = tid & 63;
    const int q = lane >> 4, p = lane & 15;
    const int nb = blockIdx.x * 64;

    for (int idx = tid; idx < 64 * 128; idx += 256) {
        int row = idx >> 7, col = idx & 127;
        float v = fr32[(size_t)(nb + row) * 128 + col] * (1.0f / NPF);
        _Float16 hi = (_Float16)v;
        Ah[row * 136 + col] = hi;
        Al[row * 136 + col] = (_Float16)(v - (float)hi);
    }
    __syncthreads();

    f16x8 ah[4], al[4];
#pragma unroll
    for (int kk = 0; kk < 4; ++kk) {
        ah[kk] = *(const f16x8*)(&Ah[(w * 16 + p) * 136 + kk * 32 + q * 8]);
        al[kk] = *(const f16x8*)(&Al[(w * 16 + p) * 136 + kk * 32 + q * 8]);
    }
    const f16x8* __restrict__ Bh = (const f16x8*)Wihh;
    const f16x8* __restrict__ Bl = (const f16x8*)Wihl;
    int dr[4];
#pragma unroll
    for (int r = 0; r < 4; ++r) {
        int m = nb + w * 16 + q * 4 + r;
        int bb = m / 96, tt = m - bb * 96;
        dr[r] = (tt * B_SZ + bb) * 384;
    }
#pragma unroll
    for (int j = 0; j < 24; ++j) {
        f32x4 cc = {0.f, 0.f, 0.f, 0.f};
#pragma unroll
        for (int kk = 0; kk < 4; ++kk)
            cc = __builtin_amdgcn_mfma_f32_16x16x32_f16(ah[kk], Bh[(j * 4 + kk) * 64 + lane], cc, 0, 0, 0);
#pragma unroll
        for (int kk = 0; kk < 4; ++kk)
            cc = __builtin_amdgcn_mfma_f32_16x16x32_f16(ah[kk], Bl[(j * 4 + kk) * 64 + lane], cc, 0, 0, 0);
#pragma unroll
        for (int kk = 0; kk < 4; ++kk)
            cc = __builtin_amdgcn_mfma_f32_16x16x32_f16(al[kk], Bh[(j * 4 + kk) * 64 + lane], cc, 0, 0, 0);
        const int o = j * 16 + p;
        const float bias = bih[o] + ((o < 256) ? bhh[o] : 0.f);
        const float scale = (o < 256) ? -1.44269504f : 1.f;
#pragma unroll
        for (int r = 0; r < 4; ++r) GIt[dr[r] + o] = (cc[r] + bias) * scale;
    }
}

// ---------------- GRU recurrence (single launch; + block-local classifier) ------
#define GRU_SYNC()                                              \
    asm volatile("s_waitcnt lgkmcnt(0)" ::: "memory");          \
    __builtin_amdgcn_s_barrier();                               \
    __builtin_amdgcn_sched_barrier(0);

#define GRU_BODY(PAR, GU, GL, JOFF)                                                                  \
    {                                                                                                \
        const _Float16* rb = hbuf[PAR];                                                              \
        _Float16* wb = hbuf[PAR ^ 1];                                                                \
        f16x8 afr[4];                                                                                \
        _Pragma("unroll") for (int kk = 0; kk < 4; ++kk)                                             \
            afr[kk] = *(const f16x8*)(&rb[c * 144 + kk * 32 + q * 8]);                               \
        const float* lp = pb + (size_t)(JOFF + 2) * STRIDE;                                          \
        _Pragma("unroll") for (int r = 0; r < 4; ++r)                                                \
            _Pragma("unroll") for (int g = 0; g < 3; ++g)                                            \
                GL[r * 3 + g] = lp[r * 384 + g * 128];                                               \
        f32x4 cc[3];                                                                                 \
        _Pragma("unroll") for (int g = 0; g < 3; ++g) {                                              \
            f32x4 a = {0.f, 0.f, 0.f, 0.f};                                                          \
            _Pragma("unroll") for (int kk = 0; kk < 4; ++kk)                                         \
                a = __builtin_amdgcn_mfma_f32_16x16x32_f16(afr[kk], bfr[g][kk], a, 0, 0, 0);         \
            cc[g] = a;                                                                               \
        }                                                                                            \
        _Pragma("unroll") for (int r = 0; r < 4; ++r) {                                              \
            float hn = cc[2][r] + bh2;                                                               \
            float rg = __builtin_amdgcn_rcpf(1.f + exp2f(fmaf(mL2E, cc[0][r], GU[r * 3 + 0])));      \
            float zg = __builtin_amdgcn_rcpf(1.f + exp2f(fmaf(mL2E, cc[1][r], GU[r * 3 + 1])));      \
            float arg = fmaf(rg, hn, GU[r * 3 + 2]);                                                 \
            float u = __builtin_amdgcn_rcpf(exp2f(2.f * L2E * arg) + 1.f);                           \
            float nn = fmaf(-2.f, u, 1.f);                                                           \
            h[r] = fmaf(zg, h[r] - nn, nn);                                                          \
            if (q < 2) wb[(q * 4 + r) * 144 + 16 * w + c] = (_Float16)h[r];                          \
        }                                                                                            \
        GRU_SYNC()                                                                                   \
    }

__global__ __launch_bounds__(512) __attribute__((amdgpu_waves_per_eu(1, 2)))
void k_gru(const float* __restrict__ GIt, const _Float16* __restrict__ Whhp,
           const float* __restrict__ bhh,
           const float* __restrict__ Wc1, const float* __restrict__ bc1,
           const float* __restrict__ Wc2, const float* __restrict__ bc2,
           float* __restrict__ out) {
    __shared__ __align__(16) _Float16 hbuf[2][16 * 144];
    const int tid = threadIdx.x;
    const int w = tid >> 6, lane = tid & 63;
    const int q = lane >> 4, c = lane & 15;
    const int B = blockIdx.x;  // batches 8B..8B+7
    const float L2E = 1.44269504f;
    const float mL2E = -1.44269504f;
    const int STRIDE = B_SZ * 384;

    f16x8 bfr[3][4];
#pragma unroll
    for (int g = 0; g < 3; ++g)
#pragma unroll
        for (int kk = 0; kk < 4; ++kk)
            bfr[g][kk] = *(const f16x8*)(Whhp + (size_t)(((w * 3 + g) * 4 + kk) * 64 + lane) * 8);
    const float bh2 = bhh[256 + 16 * w + c];
    for (int i = tid; i < 2 * 16 * 144 / 2; i += 512) ((unsigned int*)hbuf)[i] = 0u;
    float h[4] = {0.f, 0.f, 0.f, 0.f};

    const int qq = (q < 2) ? q : 1;
    const float* pb = GIt + (size_t)(B * 8 + qq * 4) * 384 + 16 * w + c;
    float g0[12], g1[12], g2[12];
#pragma unroll
    for (int r = 0; r < 4; ++r)
#pragma unroll
        for (int g = 0; g < 3; ++g) {
            g0[r * 3 + g] = pb[r * 384 + g * 128];
            g1[r * 3 + g] = pb[STRIDE + r * 384 + g * 128];
        }
    GRU_SYNC()

    for (int it = 0; it < T_SZ / 6; ++it) {
        GRU_BODY(0, g0, g2, 0)
        GRU_BODY(1, g1, g0, 1)
        GRU_BODY(0, g2, g1, 2)
        GRU_BODY(1, g0, g2, 3)
        GRU_BODY(0, g1, g0, 4)
        GRU_BODY(1, g2, g1, 5)
        pb += 6 * (size_t)STRIDE;
    }

    // ---- block-local classifier: this block owns batches 8B..8B+7 entirely ----
    float* hbf = (float*)hbuf;        // 8 x 128 f32 = 4KB
    float* hid = hbf + 1024;          // 8 x 64 f32 = 2KB
    __syncthreads();
    if (q < 2) {
#pragma unroll
        for (int r = 0; r < 4; ++r) hbf[(q * 4 + r) * 128 + 16 * w + c] = h[r];
    }
    __syncthreads();
    {
        const int b = tid >> 6, j = tid & 63;  // 512 threads = 8 batches x 64 cols
        const float* hb = hbf + b * 128;
        float a0 = bc1[j], a1 = 0.f, a2 = 0.f, a3 = 0.f;
#pragma unroll
        for (int k = 0; k < 128; k += 4) {
            a0 = fmaf(hb[k], Wc1[k * 64 + j], a0);
            a1 = fmaf(hb[k + 1], Wc1[(k + 1) * 64 + j], a1);
            a2 = fmaf(hb[k + 2], Wc1[(k + 2) * 64 + j], a2);
            a3 = fmaf(hb[k + 3], Wc1[(k + 3) * 64 + j], a3);
        }
        hid[tid] = fmaxf((a0 + a1) + (a2 + a3), 0.f);
    }
    __syncthreads();
    if (tid < 80) {
        int b = tid / 10, cc2 = tid % 10;
        float a = bc2[cc2];
#pragma unroll 8
        for (int k = 0; k < 64; ++k) a = fmaf(hid[b * 64 + k], Wc2[k * 10 + cc2], a);
        out[(B * 8 + b) * 10 + cc2] = a;
    }
}

extern "C" void kernel_launch(void* const* d_in, const int* in_sizes, int n_in, void* d_out, int out_size, void* d_ws,
                              size_t ws_size, hipStream_t stream) {
    const float* x = (const float*)d_in[0];
    const int* ei = (const int*)d_in[1];
    const int* e_src = ei;
    const int* e_dst = ei + E_TOT;
    const float* W0 = (const float*)d_in[2];
    const float* b0 = (const float*)d_in[3];
    const float* W1 = (const float*)d_in[4];
    const float* b1 = (const float*)d_in[5];
    const float* Wm = (const float*)d_in[6];
    const float* bm = (const float*)d_in[7];
    const float* Wih = (const float*)d_in[8];
    const float* Whh = (const float*)d_in[9];
    const float* bih = (const float*)d_in[10];
    const float* bhh = (const float*)d_in[11];
    const float* Wc1 = (const float*)d_in[12];
    const float* bc1 = (const float*)d_in[13];
    const float* Wc2 = (const float*)d_in[14];
    const float* bc2 = (const float*)d_in[15];
    float* out = (float*)d_out;

    char* base = (char*)d_ws;
    size_t off = 0;
    auto alloc = [&](size_t bytes) {
        size_t o = off;
        off = (off + bytes + 255) & ~(size_t)255;
        return o;
    };
    size_t o_gcur = alloc(256 * 4);
    size_t o_row2 = alloc((size_t)NN_TOT * 8);
    size_t o_er = alloc((size_t)NBINS * CAP * 4);      // padded per-bin src-only records
    size_t o_ertmp = alloc((size_t)NBINS * CAP * 4);   // padded per-bin packed (src|ldst<<18)
    size_t o_xd = alloc((size_t)NN_TOT * 16);
    size_t o_fr32 = alloc((size_t)B_SZ * T_SZ * 128 * 4);      // frame pool accumulator (f32)
    size_t o_gi = alloc((size_t)(T_SZ + 2) * B_SZ * 384 * 4);  // +2 steps: branchless tail prefetch
    size_t o_wihh = alloc((size_t)384 * 128 * 2);
    size_t o_wihl = alloc((size_t)384 * 128 * 2);
    size_t o_w1p = alloc((size_t)128 * 128 * 2);
    size_t o_wmp = alloc((size_t)128 * 128 * 2);
    size_t o_whhp = alloc((size_t)128 * 384 * 2);
    size_t o_w0h = alloc((size_t)384 * 2);
    size_t o_b0h = alloc((size_t)128 * 2);
    size_t o_z0 = alloc((size_t)NN_TOT * 16);
    if (off > ws_size) return;

    int* gcur = (int*)(base + o_gcur);
    int2* row2 = (int2*)(base + o_row2);
    int* er = (int*)(base + o_er);
    int* er_tmp = (int*)(base + o_ertmp);
    float4* xd = (float4*)(base + o_xd);
    float* fr32 = (float*)(base + o_fr32);
    float* GIt = (float*)(base + o_gi);
    _Float16* Wihh = (_Float16*)(base + o_wihh);
    _Float16* Wihl = (_Float16*)(base + o_wihl);
    _Float16* W1p = (_Float16*)(base + o_w1p);
    _Float16* Wmp = (_Float16*)(base + o_wmp);
    _Float16* Whhp = (_Float16*)(base + o_whhp);
    _Float16* W0h = (_Float16*)(base + o_w0h);
    _Float16* b0h = (_Float16*)(base + o_b0h);
    float4* z0 = (float4*)(base + o_z0);

    hipMemsetAsync(base + o_gcur, 0, 256 * 4, stream);  // bin cursors only (fr32 zeroed in k_scatter)

    k_scatter<<<NSB + 192, 256, 0, stream>>>(e_src, e_dst, gcur, er_tmp,
                                             Wih, Whh, W1, Wm, W0, b0,
                                             Wihh, Wihl, W1p, Wmp, Whhp, W0h, b0h, (float4*)fr32);
    k_binsort2<<<NBINS, 256, 0, stream>>>(er_tmp, gcur, x, er, row2, xd);
    k_z0<<<NN_TOT / 64, 256, 0, stream>>>(xd, row2, er, z0);
    k_agg_mm<<<NN_TOT / 64, 256, 0, stream>>>(z0, row2, er, W0h, b0h, W1p, b1, Wmp, bm, fr32);
    k_gi<<<B_SZ * T_SZ / 64, 256, 0, stream>>>(fr32, Wihh, Wihl, bih, bhh, GIt);
    k_gru<<<4, 512, 0, stream>>>(GIt, Whhp, bhh, Wc1, bc1, Wc2, bc2, out);
}

// Round 15
// 310.210 us; speedup vs baseline: 1.1927x; 1.0906x over previous
//
#include <hip/hip_runtime.h>

#define NN_TOT 208896      // 32*96*68 nodes
#define E_TOT  1671168     // NN_TOT*8 edges
#define B_SZ   32
#define T_SZ   96
#define NPF    68          // nodes per frame
#define HID    128
#define NBINS  204         // 208896 / 1024 nodes per bin
#define CAP    9216        // padded per-bin capacity: mean 8192 + 11 sigma (overflow p ~ 1e-27)
#define NSB    816         // scatter blocks = E_TOT / 2048

typedef _Float16 f16x8 __attribute__((ext_vector_type(8)));
typedef _Float16 f16x2v __attribute__((ext_vector_type(2)));
typedef float f32x4 __attribute__((ext_vector_type(4)));

// ---------------- single-pass scatter into padded bins (+ fused weight prep + fr32 zero) ----------
__global__ __launch_bounds__(256) void k_scatter(const int* __restrict__ src, const int* __restrict__ dst,
                                                 int* __restrict__ gcur, int* __restrict__ er_tmp,
                                                 const float* __restrict__ Wih, const float* __restrict__ Whh,
                                                 const float* __restrict__ W1, const float* __restrict__ Wm,
                                                 const float* __restrict__ W0, const float* __restrict__ b0,
                                                 _Float16* __restrict__ Wihh, _Float16* __restrict__ Wihl,
                                                 _Float16* __restrict__ W1p, _Float16* __restrict__ Wmp,
                                                 _Float16* __restrict__ Whhp, _Float16* __restrict__ W0h,
                                                 _Float16* __restrict__ b0h, float4* __restrict__ fr32v) {
    const int bid = blockIdx.x;
    const int tid = threadIdx.x;
    if (bid >= NSB) {
        // ---- weight prep (uniform per-block branch) ----
        int i = (bid - NSB) * 256 + tid;  // 0..49151
        {
            // fr32 zero-fill: 2 float4 per thread -> 49152*8 = 393216 floats exactly
            const float4 z4 = make_float4(0.f, 0.f, 0.f, 0.f);
            fr32v[(size_t)i * 2] = z4;
            fr32v[(size_t)i * 2 + 1] = z4;
        }
        {
            int e = i & 7;
            int lane = (i >> 3) & 63;
            int f = i >> 9;  // 0..95
            int j = f >> 2, kk = f & 3;
            int q = lane >> 4, p = lane & 15;
            float wv = Wih[(size_t)(j * 16 + p) * 128 + kk * 32 + q * 8 + e];
            _Float16 hi = (_Float16)wv;
            Wihh[i] = hi;
            Wihl[i] = (_Float16)(wv - (float)hi);
        }
        {
            int e = i & 7;
            int lane = (i >> 3) & 63;
            int f = i >> 9;  // 0..95
            int kk = f & 3, g = (f >> 2) % 3, wv = f / 12;
            int q = lane >> 4, c = lane & 15;
            Whhp[i] = (_Float16)Whh[(size_t)(g * 128 + 16 * wv + c) * 128 + kk * 32 + q * 8 + e];
        }
        if (i < 16384) {
            int f = i >> 9;          // frag id 0..31
            int j = f >> 2, kk = f & 3;
            int lane = (i >> 3) & 63;
            int e = i & 7;
            int q = lane >> 4, p = lane & 15;
            int k = kk * 32 + q * 8 + e, n = j * 16 + p;
            W1p[i] = (_Float16)W1[k * 128 + n];
            Wmp[i] = (_Float16)Wm[k * 128 + n];
        }
        if (i < 384) W0h[i] = (_Float16)W0[i];
        if (i < 128) b0h[i] = (_Float16)b0[i];
        return;
    }
    __shared__ int hist[NBINS];
    __shared__ int lofs[NBINS];
    __shared__ int lbase[NBINS];
    __shared__ int ts[256];
    __shared__ int recs[2048];
    __shared__ int dsta[2048];
    for (int i = tid; i < NBINS; i += 256) hist[i] = 0;
    __syncthreads();
    const int be = bid * 2048 + tid * 8;
    int s[8], d[8], rk[8];
    *(int4*)&s[0] = *(const int4*)&src[be];
    *(int4*)&s[4] = *(const int4*)&src[be + 4];
    *(int4*)&d[0] = *(const int4*)&dst[be];
    *(int4*)&d[4] = *(const int4*)&dst[be + 4];
#pragma unroll
    for (int j = 0; j < 8; ++j) rk[j] = atomicAdd(&hist[d[j] >> 10], 1);
    __syncthreads();
    // block-local exclusive scan of bin histogram (204 bins, 256 threads)
    {
        int v = (tid < NBINS) ? hist[tid] : 0;
        ts[tid] = v;
        __syncthreads();
        int inc = v;
        for (int off = 1; off < 256; off <<= 1) {
            int add = (tid >= off) ? ts[tid - off] : 0;
            __syncthreads();
            inc += add;
            ts[tid] = inc;
            __syncthreads();
        }
        if (tid < NBINS) lofs[tid] = inc - v;
    }
    // reserve global bin runs
    for (int i = tid; i < NBINS; i += 256) lbase[i] = atomicAdd(&gcur[i], hist[i]);
    __syncthreads();
    // stage records + final global addresses, grouped by bin
#pragma unroll
    for (int j = 0; j < 8; ++j) {
        int b = d[j] >> 10;
        int pos = lofs[b] + rk[j];
        recs[pos] = s[j] | ((d[j] & 1023) << 18);
        dsta[pos] = b * CAP + lbase[b] + rk[j];
    }
    __syncthreads();
    // flush: consecutive LDS positions -> consecutive global addresses within each bin run
#pragma unroll
    for (int it = 0; it < 8; ++it) {
        int p = tid + it * 256;
        er_tmp[dsta[p]] = recs[p];
    }
}

// ---------------- CSR pass C: rank captured in the counting pass (no second atomic pass) ----
__global__ __launch_bounds__(256) void k_binsort2(const int* __restrict__ er_tmp, const int* __restrict__ gcur,
                                                  const float* __restrict__ x, int* __restrict__ er,
                                                  int2* __restrict__ row2, float4* __restrict__ xd) {
    __shared__ int lcnt[1024];
    __shared__ int lofs[1024];   // row-start offsets (read-only after scan)
    __shared__ int ts[256];
    const int tid = threadIdx.x;
    const int nb = blockIdx.x << 10;
    const int base0 = blockIdx.x * CAP;
    for (int i = tid; i < 1024; i += 256) lcnt[i] = 0;
    __syncthreads();
    const int nrec = gcur[blockIdx.x];
    int rec[36];  // 36*256 == CAP
    int rnk[36];  // within-node rank from the counting atomicAdd
#pragma unroll
    for (int j = 0; j < 36; ++j) {
        int idx = tid + j * 256;
        rec[j] = (idx < nrec) ? er_tmp[base0 + idx] : -1;
    }
#pragma unroll
    for (int j = 0; j < 36; ++j)
        rnk[j] = (rec[j] >= 0) ? atomicAdd(&lcnt[rec[j] >> 18], 1) : 0;
    __syncthreads();
    const int base = tid * 4;
    const int c0 = lcnt[base], c1 = lcnt[base + 1], c2 = lcnt[base + 2], c3 = lcnt[base + 3];
    int ssum = c0 + c1 + c2 + c3;
    ts[tid] = ssum;
    __syncthreads();
    int inc = ssum;
    for (int off = 1; off < 256; off <<= 1) {
        int add = (tid >= off) ? ts[tid - off] : 0;
        __syncthreads();
        inc += add;
        ts[tid] = inc;
        __syncthreads();
    }
    const int b0 = base0 + (inc - ssum);
    lofs[base] = b0;
    lofs[base + 1] = b0 + c0;
    lofs[base + 2] = b0 + c0 + c1;
    lofs[base + 3] = b0 + c0 + c1 + c2;
    row2[nb + base] = make_int2(b0, b0 + c0);
    row2[nb + base + 1] = make_int2(b0 + c0, b0 + c0 + c1);
    row2[nb + base + 2] = make_int2(b0 + c0 + c1, b0 + c0 + c1 + c2);
    row2[nb + base + 3] = make_int2(b0 + c0 + c1 + c2, b0 + ssum);
    {
        const float4* xv = (const float4*)(x + 3 * (size_t)(nb + base));
        float4 a = xv[0], b = xv[1], c = xv[2];
        float i0 = 1.0f / sqrtf(1.f + (float)c0);
        float i1 = 1.0f / sqrtf(1.f + (float)c1);
        float i2 = 1.0f / sqrtf(1.f + (float)c2);
        float i3 = 1.0f / sqrtf(1.f + (float)c3);
        xd[nb + base + 0] = make_float4(a.x * i0, a.y * i0, a.z * i0, i0);
        xd[nb + base + 1] = make_float4(a.w * i1, b.x * i1, b.y * i1, i1);
        xd[nb + base + 2] = make_float4(b.z * i2, b.w * i2, c.x * i2, i2);
        xd[nb + base + 3] = make_float4(c.y * i3, c.z * i3, c.w * i3, i3);
    }
    __syncthreads();
#pragma unroll
    for (int j = 0; j < 36; ++j)
        if (rec[j] >= 0) er[lofs[rec[j] >> 18] + rnk[j]] = rec[j] & 0x3FFFF;
}

// ---------------- z0: 3-dim GCN0 aggregate, factorized norm ----------------
__global__ __launch_bounds__(256) void k_z0(const float4* __restrict__ xd, const int2* __restrict__ row2,
                                            const int* __restrict__ er, float4* __restrict__ z0out) {
    const int tid = threadIdx.x;
    const int blk = blockIdx.x;
    const int li = tid >> 2;
    const int slot = tid & 3;
    const int n = blk * 64 + li;
    const int2 be2 = row2[n];
    float p0 = 0.f, p1 = 0.f, p2 = 0.f;
    for (int ei = be2.x + slot; ei < be2.y; ei += 4) {
        float4 f = xd[er[ei]];
        p0 += f.x;
        p1 += f.y;
        p2 += f.z;
    }
    p0 += __shfl_xor(p0, 1); p1 += __shfl_xor(p1, 1); p2 += __shfl_xor(p2, 1);
    p0 += __shfl_xor(p0, 2); p1 += __shfl_xor(p1, 2); p2 += __shfl_xor(p2, 2);
    if (slot == 0) {
        const float4 own = xd[n];
        const float w = own.w;
        float4 z;
        z.x = w * (p0 + own.x);
        z.y = w * (p1 + own.y);
        z.z = w * (p2 + own.z);
        z.w = w;
        z0out[n] = z;
    }
}

// ---------------- fused: aggregation + GEMM1 + GEMM2 + frame-pool atomics ----------------
__global__ __launch_bounds__(256, 4) void k_agg_mm(const float4* __restrict__ z0, const int2* __restrict__ row2,
                                                   const int* __restrict__ er, const _Float16* __restrict__ W0h,
                                                   const _Float16* __restrict__ b0h, const _Float16* __restrict__ W1p,
                                                   const float* __restrict__ b1, const _Float16* __restrict__ Wmp,
                                                   const float* __restrict__ bm, float* __restrict__ fr32) {
    __shared__ __align__(16) _Float16 As[64 * 136];
    __shared__ __align__(16) _Float16 Bs[64 * 136];
    __shared__ float colpart[4 * 2 * 128];  // [wave][frame 0/1][col]
    const int tid = threadIdx.x;
    const int w = tid >> 6, lane = tid & 63;
    const int blk = blockIdx.x;

    // phase 1: per-lane edge loop, packed f16, all 32 cols in one pass (software-pipelined)
    {
        const int node = blk * 64 + lane;
        const int2 be2 = row2[node];
        const int beg = be2.x, end = be2.y;
        int ei = beg;
        int sa_c = 0, sb_c = 0, sa_n = 0, sb_n = 0;
        float4 za_c, zb_c;
        if (ei + 2 <= end) { sa_c = er[ei]; sb_c = er[ei + 1]; }
        if (ei + 4 <= end) { sa_n = er[ei + 2]; sb_n = er[ei + 3]; }
        const float4 zs = z0[node];
        if (ei + 2 <= end) { za_c = z0[sa_c]; zb_c = z0[sb_c]; }

        const f16x2v* __restrict__ W0p = (const f16x2v*)W0h;
        const f16x2v* __restrict__ b0p = (const f16x2v*)b0h;
        const int pb = w * 16;
        const f16x2v zero2 = {(_Float16)0.f, (_Float16)0.f};
        f16x2v w0p[16], w1p[16], w2p[16], bbp[16];
#pragma unroll
        for (int j = 0; j < 16; ++j) {
            w0p[j] = W0p[pb + j];
            w1p[j] = W0p[64 + pb + j];
            w2p[j] = W0p[128 + pb + j];
            bbp[j] = b0p[pb + j];
        }
        const _Float16 isd = (_Float16)zs.w;
        const f16x2v dnn = {isd, isd};
        f16x2v accp[16];
        {
            _Float16 sx = (_Float16)zs.x, sy = (_Float16)zs.y, sz = (_Float16)zs.z;
            f16x2v zxx = {sx, sx}, zyy = {sy, sy}, zzz = {sz, sz};
#pragma unroll
            for (int j = 0; j < 16; ++j) {
                f16x2v t = zxx * w0p[j] + (zyy * w1p[j] + (zzz * w2p[j] + bbp[j]));
                t = __builtin_elementwise_max(t, zero2);
                accp[j] = t * dnn;
            }
        }
        for (; ei + 2 <= end; ei += 2) {
            float4 za_nv, zb_nv;
            int sa_nn = 0, sb_nn = 0;
            if (ei + 4 <= end) { za_nv = z0[sa_n]; zb_nv = z0[sb_n]; }
            if (ei + 6 <= end) { sa_nn = er[ei + 4]; sb_nn = er[ei + 5]; }
            const float4 za = za_c, zb = zb_c;
            _Float16 ax = (_Float16)za.x, ay = (_Float16)za.y, az = (_Float16)za.z;
            _Float16 aen = (_Float16)za.w;
            _Float16 bx = (_Float16)zb.x, by = (_Float16)zb.y, bz = (_Float16)zb.z;
            _Float16 ben = (_Float16)zb.w;
            f16x2v axx = {ax, ax}, ayy = {ay, ay}, azz = {az, az}, aee = {aen, aen};
            f16x2v bxx = {bx, bx}, byy = {by, by}, bzz = {bz, bz}, bee = {ben, ben};
#pragma unroll
            for (int j = 0; j < 16; ++j) {
                f16x2v t = axx * w0p[j] + (ayy * w1p[j] + (azz * w2p[j] + bbp[j]));
                t = __builtin_elementwise_max(t, zero2);
                accp[j] = t * aee + accp[j];
            }
#pragma unroll
            for (int j = 0; j < 16; ++j) {
                f16x2v t = bxx * w0p[j] + (byy * w1p[j] + (bzz * w2p[j] + bbp[j]));
                t = __builtin_elementwise_max(t, zero2);
                accp[j] = t * bee + accp[j];
            }
            za_c = za_nv; zb_c = zb_nv;
            sa_n = sa_nn; sb_n = sb_nn;
        }
        if (ei < end) {
            float4 za = z0[er[ei]];
            _Float16 ax = (_Float16)za.x, ay = (_Float16)za.y, az = (_Float16)za.z;
            _Float16 aen = (_Float16)za.w;
            f16x2v axx = {ax, ax}, ayy = {ay, ay}, azz = {az, az}, aee = {aen, aen};
#pragma unroll
            for (int j = 0; j < 16; ++j) {
                f16x2v t = axx * w0p[j] + (ayy * w1p[j] + (azz * w2p[j] + bbp[j]));
                t = __builtin_elementwise_max(t, zero2);
                accp[j] = t * aee + accp[j];
            }
        }
        _Float16* dst = &As[lane * 136 + w * 32];
#pragma unroll
        for (int j = 0; j < 16; ++j) *(f16x2v*)(dst + 2 * j) = accp[j] * dnn;
    }
    __syncthreads();

    // phase 2: GEMM1 (As @ W1p + b1, relu) -> Bs (wave-local rows, 136-stride)
    const int q = lane >> 4, c = lane & 15;
    {
        f16x8 afr[4];
#pragma unroll
        for (int kk = 0; kk < 4; ++kk) afr[kk] = *(const f16x8*)(&As[(w * 16 + c) * 136 + kk * 32 + q * 8]);
        const f16x8* __restrict__ Bv = (const f16x8*)W1p;
#pragma unroll
        for (int j = 0; j < 8; ++j) {
            f32x4 cc = {0.f, 0.f, 0.f, 0.f};
#pragma unroll
            for (int kk = 0; kk < 4; ++kk)
                cc = __builtin_amdgcn_mfma_f32_16x16x32_f16(afr[kk], Bv[(j * 4 + kk) * 64 + lane], cc, 0, 0, 0);
            const float bi = b1[j * 16 + c];
#pragma unroll
            for (int r = 0; r < 4; ++r)
                Bs[(w * 16 + q * 4 + r) * 136 + j * 16 + c] = (_Float16)fmaxf(cc[r] + bi, 0.f);
        }
    }
    // Bs rows w*16..w*16+15 are wave-local -> no barrier needed.

    // phase 3: GEMM2 (Bs @ Wmp + bm, relu) + segmented per-frame column sums
    {
        f16x8 afr2[4];
#pragma unroll
        for (int kk = 0; kk < 4; ++kk) afr2[kk] = *(const f16x8*)(&Bs[(w * 16 + c) * 136 + kk * 32 + q * 8]);
        const f16x8* __restrict__ Bv2 = (const f16x8*)Wmp;
        const int f0 = (blk * 64) / NPF;
        const int cut = (f0 + 1) * NPF;          // first node of frame f0+1
        const int rowg0 = blk * 64 + w * 16 + q * 4;
#pragma unroll
        for (int j = 0; j < 8; ++j) {
            f32x4 cc = {0.f, 0.f, 0.f, 0.f};
#pragma unroll
            for (int kk = 0; kk < 4; ++kk)
                cc = __builtin_amdgcn_mfma_f32_16x16x32_f16(afr2[kk], Bv2[(j * 4 + kk) * 64 + lane], cc, 0, 0, 0);
            const float bi = bm[j * 16 + c];
            float sA = 0.f, sB = 0.f;
#pragma unroll
            for (int r = 0; r < 4; ++r) {
                float v = fmaxf(cc[r] + bi, 0.f);
                if (rowg0 + r < cut) sA += v; else sB += v;
            }
            sA += __shfl_xor(sA, 16);
            sA += __shfl_xor(sA, 32);
            sB += __shfl_xor(sB, 16);
            sB += __shfl_xor(sB, 32);
            if (lane < 16) {
                colpart[(w * 2 + 0) * 128 + j * 16 + c] = sA;
                colpart[(w * 2 + 1) * 128 + j * 16 + c] = sB;
            }
        }
    }
    __syncthreads();
    {
        const int f = tid >> 7, col = tid & 127;  // 256 threads = 2 frames x 128 cols
        float s = colpart[(0 * 2 + f) * 128 + col] + colpart[(1 * 2 + f) * 128 + col] +
                  colpart[(2 * 2 + f) * 128 + col] + colpart[(3 * 2 + f) * 128 + col];
        const int f0 = (blk * 64) / NPF;
        if (f == 0) {
            atomicAdd(&fr32[(size_t)f0 * 128 + col], s);
        } else {
            const int f1 = (blk * 64 + 63) / NPF;
            if (f1 != f0) atomicAdd(&fr32[(size_t)f1 * 128 + col], s);
        }
    }
}

// ---------------- gi GEMM: fr32 (mean-scaled, split to hi/lo f16 in-LDS) @ Wih^T -> GIt ----
__global__ __launch_bounds__(256) void k_gi(const float* __restrict__ fr32,
                                            const _Float16* __restrict__ Wihh, const _Float16* __restrict__ Wihl,
                                            const float* __restrict__ bih, const float* __restrict__ bhh,
                                            float* __restrict__ GIt) {
    __shared__ __align__(16) _Float16 Ah[64 * 136];
    __shared__ __align__(16) _Float16 Al[64 * 136];
    const int tid = threadIdx.x;
    const int w = tid >> 6, lane = tid & 63;
    const int q = lane >> 4, p = lane & 15;
    const int nb = blockIdx.x * 64;

    for (int idx = tid; idx < 64 * 128; idx += 256) {
        int row = idx >> 7, col = idx & 127;
        float v = fr32[(size_t)(nb + row) * 128 + col] * (1.0f / NPF);
        _Float16 hi = (_Float16)v;
        Ah[row * 136 + col] = hi;
        Al[row * 136 + col] = (_Float16)(v - (float)hi);
    }
    __syncthreads();

    f16x8 ah[4], al[4];
#pragma unroll
    for (int kk = 0; kk < 4; ++kk) {
        ah[kk] = *(const f16x8*)(&Ah[(w * 16 + p) * 136 + kk * 32 + q * 8]);
        al[kk] = *(const f16x8*)(&Al[(w * 16 + p) * 136 + kk * 32 + q * 8]);
    }
    const f16x8* __restrict__ Bh = (const f16x8*)Wihh;
    const f16x8* __restrict__ Bl = (const f16x8*)Wihl;
    int dr[4];
#pragma unroll
    for (int r = 0; r < 4; ++r) {
        int m = nb + w * 16 + q * 4 + r;
        int bb = m / 96, tt = m - bb * 96;
        dr[r] = (tt * B_SZ + bb) * 384;
    }
#pragma unroll
    for (int j = 0; j < 24; ++j) {
        f32x4 cc = {0.f, 0.f, 0.f, 0.f};
#pragma unroll
        for (int kk = 0; kk < 4; ++kk)
            cc = __builtin_amdgcn_mfma_f32_16x16x32_f16(ah[kk], Bh[(j * 4 + kk) * 64 + lane], cc, 0, 0, 0);
#pragma unroll
        for (int kk = 0; kk < 4; ++kk)
            cc = __builtin_amdgcn_mfma_f32_16x16x32_f16(ah[kk], Bl[(j * 4 + kk) * 64 + lane], cc, 0, 0, 0);
#pragma unroll
        for (int kk = 0; kk < 4; ++kk)
            cc = __builtin_amdgcn_mfma_f32_16x16x32_f16(al[kk], Bh[(j * 4 + kk) * 64 + lane], cc, 0, 0, 0);
        const int o = j * 16 + p;
        const float bias = bih[o] + ((o < 256) ? bhh[o] : 0.f);
        const float scale = (o < 256) ? -1.44269504f : 1.f;
#pragma unroll
        for (int r = 0; r < 4; ++r) GIt[dr[r] + o] = (cc[r] + bias) * scale;
    }
}

// ---------------- GRU recurrence: 8 blocks x 4 batches — per-CU issue halved ------
// Theory (R2/R3/R4 post-mortems): step wall is ISSUE-bound per SIMD, not chain-bound.
// Each thread owns exactly one (batch=q, col=w*16+c) h-state: 3 transcendentals/thread
// (was 12), 3 GIt loads/thread (was 12). MFMA per wave unchanged (12; A rows 4-15 zero).
// Gate-pre values (C rows 0-3, resident in lanes 0-15) reach all lanes via 12 static
// shuffles + a q-select (rule #20-safe static indexing). Math is bit-identical.
#define GRU_SYNC()                                              \
    asm volatile("s_waitcnt lgkmcnt(0)" ::: "memory");          \
    __builtin_amdgcn_s_barrier();                               \
    __builtin_amdgcn_sched_barrier(0);

#define GRU_BODY(PAR, GU, GL, JOFF)                                                                  \
    {                                                                                                \
        const _Float16* rb = hbuf[PAR];                                                              \
        _Float16* wb = hbuf[PAR ^ 1];                                                                \
        f16x8 afr[4];                                                                                \
        _Pragma("unroll") for (int kk = 0; kk < 4; ++kk)                                             \
            afr[kk] = *(const f16x8*)(&rb[c * 144 + kk * 32 + q * 8]);                               \
        const float* lp = pb + (size_t)(JOFF + 2) * STRIDE;                                          \
        _Pragma("unroll") for (int g = 0; g < 3; ++g) GL[g] = lp[g * 128];                           \
        f32x4 cc[3];                                                                                 \
        _Pragma("unroll") for (int g = 0; g < 3; ++g) {                                              \
            f32x4 a = {0.f, 0.f, 0.f, 0.f};                                                          \
            _Pragma("unroll") for (int kk = 0; kk < 4; ++kk)                                         \
                a = __builtin_amdgcn_mfma_f32_16x16x32_f16(afr[kk], bfr[g][kk], a, 0, 0, 0);         \
            cc[g] = a;                                                                               \
        }                                                                                            \
        float sg[3];                                                                                 \
        _Pragma("unroll") for (int g = 0; g < 3; ++g) {                                              \
            float x0 = __shfl(cc[g][0], c);                                                          \
            float x1 = __shfl(cc[g][1], c);                                                          \
            float x2 = __shfl(cc[g][2], c);                                                          \
            float x3 = __shfl(cc[g][3], c);                                                          \
            sg[g] = (q == 0) ? x0 : (q == 1) ? x1 : (q == 2) ? x2 : x3;                              \
        }                                                                                            \
        {                                                                                            \
            float hn = sg[2] + bh2;                                                                  \
            float rg = __builtin_amdgcn_rcpf(1.f + exp2f(fmaf(mL2E, sg[0], GU[0])));                 \
            float zg = __builtin_amdgcn_rcpf(1.f + exp2f(fmaf(mL2E, sg[1], GU[1])));                 \
            float arg = fmaf(rg, hn, GU[2]);                                                         \
            float u = __builtin_amdgcn_rcpf(exp2f(2.f * L2E * arg) + 1.f);                           \
            float nn = fmaf(-2.f, u, 1.f);                                                           \
            h = fmaf(zg, h - nn, nn);                                                                \
            wb[q * 144 + gcol] = (_Float16)h;                                                        \
        }                                                                                            \
        GRU_SYNC()                                                                                   \
    }

__global__ __launch_bounds__(512) __attribute__((amdgpu_waves_per_eu(1, 2)))
void k_gru(const float* __restrict__ GIt, const _Float16* __restrict__ Whhp,
           const float* __restrict__ bhh,
           const float* __restrict__ Wc1, const float* __restrict__ bc1,
           const float* __restrict__ Wc2, const float* __restrict__ bc2,
           float* __restrict__ out) {
    __shared__ __align__(16) _Float16 hbuf[2][16 * 144];
    const int tid = threadIdx.x;
    const int w = tid >> 6, lane = tid & 63;
    const int q = lane >> 4, c = lane & 15;
    const int B = blockIdx.x;  // batches 4B..4B+3
    const float L2E = 1.44269504f;
    const float mL2E = -1.44269504f;
    const int STRIDE = B_SZ * 384;

    // B-frags: wave w handles output n-tiles {g*8+w} = cols w*16..w*16+15 per gate (same pack)
    f16x8 bfr[3][4];
#pragma unroll
    for (int g = 0; g < 3; ++g)
#pragma unroll
        for (int kk = 0; kk < 4; ++kk)
            bfr[g][kk] = *(const f16x8*)(Whhp + (size_t)(((w * 3 + g) * 4 + kk) * 64 + lane) * 8);
    const int gcol = w * 16 + c;               // this thread's h column
    const float bh2 = bhh[256 + gcol];         // n-gate hh-bias
    for (int i = tid; i < 2 * 16 * 144 / 2; i += 512) ((unsigned int*)hbuf)[i] = 0u;  // BOTH buffers
    float h = 0.f;                             // one (batch=q, col=gcol) state per thread

    const float* pb = GIt + (size_t)(B * 4 + q) * 384 + gcol;
    float g0[3], g1[3], g2[3];
#pragma unroll
    for (int g = 0; g < 3; ++g) {
        g0[g] = pb[g * 128];            // t = 0
        g1[g] = pb[STRIDE + g * 128];   // t = 1
    }
    GRU_SYNC()

    for (int it = 0; it < T_SZ / 6; ++it) {
        GRU_BODY(0, g0, g2, 0)
        GRU_BODY(1, g1, g0, 1)
        GRU_BODY(0, g2, g1, 2)
        GRU_BODY(1, g0, g2, 3)
        GRU_BODY(0, g1, g0, 4)
        GRU_BODY(1, g2, g1, 5)
        pb += 6 * (size_t)STRIDE;
    }

    // ---- block-local classifier: this block owns batches 4B..4B+3 entirely ----
    float* hbf = (float*)hbuf;        // 4 x 128 f32 = 2KB
    float* hid = hbf + 512;           // 4 x 64 f32 = 1KB
    __syncthreads();
    hbf[q * 128 + gcol] = h;          // all 512 threads write 512 distinct slots
    __syncthreads();
    if (tid < 256) {
        const int b = tid >> 6, j = tid & 63;  // 4 batches x 64 cols
        const float* hb = hbf + b * 128;
        float a0 = bc1[j], a1 = 0.f, a2 = 0.f, a3 = 0.f;
#pragma unroll
        for (int k = 0; k < 128; k += 4) {
            a0 = fmaf(hb[k], Wc1[k * 64 + j], a0);
            a1 = fmaf(hb[k + 1], Wc1[(k + 1) * 64 + j], a1);
            a2 = fmaf(hb[k + 2], Wc1[(k + 2) * 64 + j], a2);
            a3 = fmaf(hb[k + 3], Wc1[(k + 3) * 64 + j], a3);
        }
        hid[tid] = fmaxf((a0 + a1) + (a2 + a3), 0.f);
    }
    __syncthreads();
    if (tid < 40) {
        int b = tid / 10, cc2 = tid % 10;
        float a = bc2[cc2];
#pragma unroll 8
        for (int k = 0; k < 64; ++k) a = fmaf(hid[b * 64 + k], Wc2[k * 10 + cc2], a);
        out[(B * 4 + b) * 10 + cc2] = a;
    }
}

extern "C" void kernel_launch(void* const* d_in, const int* in_sizes, int n_in, void* d_out, int out_size, void* d_ws,
                              size_t ws_size, hipStream_t stream) {
    const float* x = (const float*)d_in[0];
    const int* ei = (const int*)d_in[1];
    const int* e_src = ei;
    const int* e_dst = ei + E_TOT;
    const float* W0 = (const float*)d_in[2];
    const float* b0 = (const float*)d_in[3];
    const float* W1 = (const float*)d_in[4];
    const float* b1 = (const float*)d_in[5];
    const float* Wm = (const float*)d_in[6];
    const float* bm = (const float*)d_in[7];
    const float* Wih = (const float*)d_in[8];
    const float* Whh = (const float*)d_in[9];
    const float* bih = (const float*)d_in[10];
    const float* bhh = (const float*)d_in[11];
    const float* Wc1 = (const float*)d_in[12];
    const float* bc1 = (const float*)d_in[13];
    const float* Wc2 = (const float*)d_in[14];
    const float* bc2 = (const float*)d_in[15];
    float* out = (float*)d_out;

    char* base = (char*)d_ws;
    size_t off = 0;
    auto alloc = [&](size_t bytes) {
        size_t o = off;
        off = (off + bytes + 255) & ~(size_t)255;
        return o;
    };
    size_t o_gcur = alloc(256 * 4);
    size_t o_row2 = alloc((size_t)NN_TOT * 8);
    size_t o_er = alloc((size_t)NBINS * CAP * 4);      // padded per-bin src-only records
    size_t o_ertmp = alloc((size_t)NBINS * CAP * 4);   // padded per-bin packed (src|ldst<<18)
    size_t o_xd = alloc((size_t)NN_TOT * 16);
    size_t o_fr32 = alloc((size_t)B_SZ * T_SZ * 128 * 4);      // frame pool accumulator (f32)
    size_t o_gi = alloc((size_t)(T_SZ + 2) * B_SZ * 384 * 4);  // +2 steps: branchless tail prefetch
    size_t o_wihh = alloc((size_t)384 * 128 * 2);
    size_t o_wihl = alloc((size_t)384 * 128 * 2);
    size_t o_w1p = alloc((size_t)128 * 128 * 2);
    size_t o_wmp = alloc((size_t)128 * 128 * 2);
    size_t o_whhp = alloc((size_t)128 * 384 * 2);
    size_t o_w0h = alloc((size_t)384 * 2);
    size_t o_b0h = alloc((size_t)128 * 2);
    size_t o_z0 = alloc((size_t)NN_TOT * 16);
    if (off > ws_size) return;

    int* gcur = (int*)(base + o_gcur);
    int2* row2 = (int2*)(base + o_row2);
    int* er = (int*)(base + o_er);
    int* er_tmp = (int*)(base + o_ertmp);
    float4* xd = (float4*)(base + o_xd);
    float* fr32 = (float*)(base + o_fr32);
    float* GIt = (float*)(base + o_gi);
    _Float16* Wihh = (_Float16*)(base + o_wihh);
    _Float16* Wihl = (_Float16*)(base + o_wihl);
    _Float16* W1p = (_Float16*)(base + o_w1p);
    _Float16* Wmp = (_Float16*)(base + o_wmp);
    _Float16* Whhp = (_Float16*)(base + o_whhp);
    _Float16* W0h = (_Float16*)(base + o_w0h);
    _Float16* b0h = (_Float16*)(base + o_b0h);
    float4* z0 = (float4*)(base + o_z0);

    hipMemsetAsync(base + o_gcur, 0, 256 * 4, stream);  // bin cursors only (fr32 zeroed in k_scatter)

    k_scatter<<<NSB + 192, 256, 0, stream>>>(e_src, e_dst, gcur, er_tmp,
                                             Wih, Whh, W1, Wm, W0, b0,
                                             Wihh, Wihl, W1p, Wmp, Whhp, W0h, b0h, (float4*)fr32);
    k_binsort2<<<NBINS, 256, 0, stream>>>(er_tmp, gcur, x, er, row2, xd);
    k_z0<<<NN_TOT / 64, 256, 0, stream>>>(xd, row2, er, z0);
    k_agg_mm<<<NN_TOT / 64, 256, 0, stream>>>(z0, row2, er, W0h, b0h, W1p, b1, Wmp, bm, fr32);
    k_gi<<<B_SZ * T_SZ / 64, 256, 0, stream>>>(fr32, Wihh, Wihl, bih, bhh, GIt);
    k_gru<<<8, 512, 0, stream>>>(GIt, Whhp, bhh, Wc1, bc1, Wc2, bc2, out);
}